// Round 9
// baseline (298.038 us; speedup 1.0000x reference)
//
#include <hip/hip_runtime.h>
#include <hip/hip_bf16.h>
#include <cstdint>

#define S_ 2048
#define M_ 512
#define L_ 2560
#define D_ 1024
#define F_ 4096
#define H_ 16
#define DH_ 64
#define W_ 256
#define NR_ 513
#define NRP_ 640

typedef unsigned int uint32;
typedef __attribute__((ext_vector_type(8))) short bf16x8;
typedef __attribute__((ext_vector_type(4))) float f32x4;

__device__ __forceinline__ ushort f2bf(float f) {
  uint32 u = __builtin_bit_cast(uint32, f);
  u += 0x7FFFu + ((u >> 16) & 1u);
  return (ushort)(u >> 16);
}
__device__ __forceinline__ float bf2f(ushort s) {
  uint32 u = ((uint32)s) << 16;
  return __builtin_bit_cast(float, u);
}
__device__ __forceinline__ ushort4 pack4(float4 vf) {
  ushort4 r;
  r.x = f2bf(vf.x); r.y = f2bf(vf.y); r.z = f2bf(vf.z); r.w = f2bf(vf.w);
  return r;
}
__device__ __forceinline__ float gelu_tanh(float x) {
  float t = 0.7978845608028654f * x * (1.f + 0.044715f * x * x);
  float e = __expf(2.f * t);
  float th = 1.f - 2.f / (e + 1.f);
  return 0.5f * x * (1.f + th);
}

// async global(16B/lane) -> LDS, wave-uniform LDS base + lane*16
__device__ __forceinline__ void gld_lds16(const ushort* g, ushort* l) {
  __builtin_amdgcn_global_load_lds((const __attribute__((address_space(1))) void*)g,
                                   (__attribute__((address_space(3))) void*)l, 16, 0, 0);
}

// ================= fused prep: 7 weight transposes + kv pack + sinusoid =================
__device__ __forceinline__ void tr_tile(const float* __restrict__ in, ushort* __restrict__ out,
                                        int R, int C, int c0, int r0, int tx, int ty,
                                        float (*tile)[33]) {
#pragma unroll
  for (int i = 0; i < 4; i++)
    tile[ty + i * 8][tx] = in[(size_t)(r0 + ty + i * 8) * C + c0 + tx];
  __syncthreads();
#pragma unroll
  for (int i = 0; i < 4; i++)
    out[(size_t)(c0 + ty + i * 8) * R + r0 + tx] = f2bf(tile[tx][ty + i * 8]);
}

__global__ __launch_bounds__(256)
void prep_kernel(const float* __restrict__ x, const float* __restrict__ mem,
                 const float* __restrict__ Wq, const float* __restrict__ Wk,
                 const float* __restrict__ Wv, const float* __restrict__ Wo,
                 const float* __restrict__ Wr, const float* __restrict__ W1,
                 const float* __restrict__ W2,
                 ushort* __restrict__ WqT, ushort* __restrict__ WkT,
                 ushort* __restrict__ WvT, ushort* __restrict__ WoT,
                 ushort* __restrict__ WrT, ushort* __restrict__ W1T,
                 ushort* __restrict__ W2T,
                 ushort* __restrict__ kvb, ushort* __restrict__ remb) {
  __shared__ float tile[32][33];
  const int bid = blockIdx.x;
  const int tid = threadIdx.x;
  const int tx = tid & 31, ty = tid >> 5;

  if (bid < 5120) {
    const int which = bid >> 10, idx = bid & 1023;
    const float* ins[5] = {Wq, Wk, Wv, Wo, Wr};
    ushort* outs[5] = {WqT, WkT, WvT, WoT, WrT};
    tr_tile(ins[which], outs[which], 1024, 1024, (idx & 31) * 32, (idx >> 5) * 32, tx, ty, tile);
  } else if (bid < 9216) {
    const int idx = bid - 5120;
    tr_tile(W1, W1T, 1024, 4096, (idx % 128) * 32, (idx / 128) * 32, tx, ty, tile);
  } else if (bid < 13312) {
    const int idx = bid - 9216;
    tr_tile(W2, W2T, 4096, 1024, (idx & 31) * 32, (idx >> 5) * 32, tx, ty, tile);
  } else if (bid < 15872) {
    const int k = (bid - 13312) * 256 + tid;
    const int l = k >> 8, c = k & 255;
    const float4* src = (l < M_) ? (const float4*)(mem + (size_t)l * D_)
                                 : (const float4*)(x + (size_t)(l - M_) * D_);
    ((ushort4*)kvb)[k] = pack4(src[c]);
  } else {
    const int idx = (bid - 15872) * 256 + tid;
    const int r = idx >> 9, f = idx & 511;
    if (r < NR_) {
      float invf = expf(-(float)f * (9.210340371976184f / 512.0f));
      float ang = (float)(r - W_) * invf;
      remb[(size_t)r * D_ + f] = f2bf(sinf(ang));
      remb[(size_t)r * D_ + 512 + f] = f2bf(cosf(ang));
    } else if (r < NRP_) {
      remb[(size_t)r * D_ + f] = 0;
      remb[(size_t)r * D_ + 512 + f] = 0;
    }
  }
}

// ====== MFMA GEMM core: BK=64, 2-phase, BM x BN tiles (BN in {64,128}) ======
// C[M,N] = A[M,K] x BT[N,K]^T, bf16 in. 1D grid with XCD-bijective swizzle.
// EPI: 0 bf16; 1 f32 (SPLITK2: z=0->Cout, z=1->Cout2); 2 bf16(gelu(c+bias));
//      3 f32(c+bias) (SPLITK2: z=1->Cout2, no bias); 5 split kb/Vt.
template <int BM, int BN, int EPI, int SPLITK>
__device__ __forceinline__
void gemm_core(const ushort* __restrict__ A, const ushort* __restrict__ BT,
               void* __restrict__ Cout, void* __restrict__ Cout2,
               const float* __restrict__ bias, int Msz, int Nsz, int Ksz, int Kstride,
               int gx, int bid, int nwg, ushort* smem) {
  constexpr int PA = BM * 8 + 16;       // halfwords per kg-block
  constexpr int PB = BN * 8 + 16;
  constexpr int MFR = BM / 32;
  constexpr int NFR = BN / 32;
  constexpr int NAI = (BM / 64) * 8;    // A stage insts per block per tile
  constexpr int NBI = (BN / 64) * 8;
  constexpr int NPW = (NAI + NBI) / 4;  // stage insts per thread
  const int tid = threadIdx.x;
  const int wave = tid >> 6, lane = tid & 63;
  const int wr = wave >> 1, wc = wave & 1;

  const int q = nwg >> 3;
  const int swz = (bid & 7) * q + (bid >> 3);
  const int gy = Msz / BM;
  const int bx = swz % gx;
  const int rest = swz / gx;
  const int by = rest % gy;
  const int bz = rest / gy;

  const int brow = by * BM, bcol = bx * BN;
  const int koff = (SPLITK == 2) ? bz * Ksz : 0;

  ushort* As = smem;                    // 2 bufs x 8*PA
  ushort* Bs = smem + 2 * 8 * PA;       // 2 bufs x 8*PB

  const ushort* gsrc[NPW]; int ldst[NPW];
#pragma unroll
  for (int i = 0; i < NPW; i++) {
    const int idx = i * 4 + wave;
    if (i < NAI / 4) {
      const int rowbase = (idx >> 3) * 64, kg = idx & 7;
      gsrc[i] = A + (size_t)(brow + rowbase + lane) * Kstride + koff + kg * 8;
      ldst[i] = kg * PA + rowbase * 8;
    } else {
      const int b = idx - NAI;
      const int rowbase = (b >> 3) * 64, kg = b & 7;
      gsrc[i] = BT + (size_t)(bcol + rowbase + lane) * Kstride + koff + kg * 8;
      ldst[i] = kg * PB + rowbase * 8;
    }
  }

  f32x4 acc[MFR][NFR] = {};
  const int kgf = lane >> 4, fr = lane & 15;
  const int nk = Ksz >> 6;              // BK = 64

  auto stage = [&](int t, int buf) {
    const int ko = t * 64;
    ushort* ab = As + buf * 8 * PA;
    ushort* bb = Bs + buf * 8 * PB;
#pragma unroll
    for (int i = 0; i < NPW; i++) {
      ushort* base = (i < NAI / 4) ? ab : bb;
      gld_lds16(gsrc[i] + ko, base + ldst[i]);
    }
  };

  stage(0, 0);
  asm volatile("s_waitcnt vmcnt(0)" ::: "memory");
  __builtin_amdgcn_s_barrier();
  __builtin_amdgcn_sched_barrier(0);

  int cur = 0;
  for (int t = 0; t < nk; t++) {
    if (t + 1 < nk) stage(t + 1, cur ^ 1);   // issue next-tile loads FIRST
    ushort* ab = As + cur * 8 * PA;
    ushort* bb = Bs + cur * 8 * PB;
#pragma unroll
    for (int kk = 0; kk < 2; kk++) {
      bf16x8 af[MFR], bfv[NFR];
#pragma unroll
      for (int m = 0; m < MFR; m++)
        af[m] = *(const bf16x8*)(ab + (kk * 4 + kgf) * PA + (wr * (BM / 2) + m * 16 + fr) * 8);
#pragma unroll
      for (int n = 0; n < NFR; n++)
        bfv[n] = *(const bf16x8*)(bb + (kk * 4 + kgf) * PB + (wc * (BN / 2) + n * 16 + fr) * 8);
#pragma unroll
      for (int m = 0; m < MFR; m++)
#pragma unroll
        for (int n = 0; n < NFR; n++)
          acc[m][n] = __builtin_amdgcn_mfma_f32_16x16x32_bf16(af[m], bfv[n], acc[m][n], 0, 0, 0);
    }
    if (t + 1 < nk) {
      asm volatile("s_waitcnt vmcnt(0)" ::: "memory");
      __builtin_amdgcn_s_barrier();
      __builtin_amdgcn_sched_barrier(0);
    }
    cur ^= 1;
  }

  const int r4 = (lane >> 4) * 4;
  float* co = (float*)Cout;
  bool addb = (EPI == 3);
  if constexpr (SPLITK == 2) {
    if (bz == 1) { co = (float*)Cout2; addb = false; }
  }
#pragma unroll
  for (int m = 0; m < MFR; m++) {
#pragma unroll
    for (int n = 0; n < NFR; n++) {
      const int col = bcol + wc * (BN / 2) + n * 16 + fr;
      if constexpr (EPI == 5) {
        if (col < 1024) {
#pragma unroll
          for (int r = 0; r < 4; r++) {
            const int row = brow + wr * (BM / 2) + m * 16 + r4 + r;
            ((ushort*)Cout)[(size_t)row * 1024 + col] = f2bf(acc[m][n][r]);
          }
        } else {
          const int row0 = brow + wr * (BM / 2) + m * 16 + r4;
          ushort4 pk;
          pk.x = f2bf(acc[m][n][0]); pk.y = f2bf(acc[m][n][1]);
          pk.z = f2bf(acc[m][n][2]); pk.w = f2bf(acc[m][n][3]);
          *(ushort4*)((ushort*)Cout2 + (size_t)(col - 1024) * Msz + row0) = pk;
        }
      } else {
#pragma unroll
        for (int r = 0; r < 4; r++) {
          const int row = brow + wr * (BM / 2) + m * 16 + r4 + r;
          float val = acc[m][n][r];
          size_t o = (size_t)row * Nsz + col;
          if constexpr (EPI == 0) ((ushort*)Cout)[o] = f2bf(val);
          else if constexpr (EPI == 2) ((ushort*)Cout)[o] = f2bf(gelu_tanh(val + bias[col]));
          else co[o] = addb ? val + bias[col] : val;
        }
      }
    }
  }
}

template <int BM, int BN, int EPI, int SPLITK>
__global__ __launch_bounds__(256)
void gemm_kern(const ushort* __restrict__ A, const ushort* __restrict__ BT,
               void* __restrict__ Cout, void* __restrict__ Cout2,
               const float* __restrict__ bias, int Msz, int Nsz, int Ksz, int Kstride,
               int gx) {
  constexpr int PA = BM * 8 + 16, PB = BN * 8 + 16;
  __shared__ __align__(16) ushort smem[2 * 8 * (PA + PB)];
  gemm_core<BM, BN, EPI, SPLITK>(A, BT, Cout, Cout2, bias, Msz, Nsz, Ksz, Kstride,
                                 gx, blockIdx.x, gridDim.x, smem);
}

// merged Q / KV / R projection, all 64x64 tiles: 512 + 1280 + 160 = 1952 blocks
__global__ __launch_bounds__(256)
void proj_gemm(const ushort* __restrict__ kvb, const ushort* __restrict__ WqT,
               const ushort* __restrict__ WkvT, const ushort* __restrict__ WrT,
               const ushort* __restrict__ remb,
               ushort* __restrict__ qb, ushort* __restrict__ kb,
               ushort* __restrict__ Vt, ushort* __restrict__ Rb) {
  __shared__ __align__(16) ushort smem[2 * 8 * (2 * (64 * 8 + 16))];
  const int bid = blockIdx.x;
  if (bid < 512) {
    gemm_core<64, 64, 0, 1>(kvb + 512 * 1024, WqT, qb, nullptr, nullptr,
                            2048, 1024, 1024, 1024, 16, bid, 512, smem);
  } else if (bid < 1792) {
    gemm_core<64, 64, 5, 1>(kvb, WkvT, kb, Vt, nullptr,
                            2560, 2048, 1024, 1024, 32, bid - 512, 1280, smem);
  } else {
    gemm_core<64, 64, 0, 1>(remb, WrT, Rb, nullptr, nullptr,
                            640, 1024, 1024, 1024, 16, bid - 1792, 160, smem);
  }
}

// ---------------- banded attention v6: lazy-max, per-lane partial l, setprio ----------
__global__ __launch_bounds__(256)
void attn_mfma4(const ushort* __restrict__ qb, const ushort* __restrict__ kb,
                const ushort* __restrict__ Vt, const ushort* __restrict__ Rb,
                const float* __restrict__ ubias, const float* __restrict__ vbias,
                ushort* __restrict__ attb) {
  const int bid = blockIdx.x;
  const int swz = (bid & 7) * 64 + (bid >> 3);
  const int h = swz >> 5;
  const int i0 = (swz & 31) * 64;
  const int tid = threadIdx.x;
  const int wave = tid >> 6, lane = tid & 63;
  const int g = lane >> 4, fr = lane & 15;
  const int hD = h * DH_;

  __shared__ __align__(16) ushort ring[4][16][64];
  __shared__ __align__(16) ushort Pl[4][16][40];

  const int qi = i0 + wave * 16 + fr;
  bf16x8 afu[2], afv[2];
#pragma unroll
  for (int kst = 0; kst < 2; kst++) {
    const int dof = kst * 32 + g * 8;
    bf16x8 qv = *(const bf16x8*)(qb + (size_t)qi * D_ + hD + dof);
    const float* up = ubias + hD + dof;
    const float* vp = vbias + hD + dof;
    bf16x8 au, av;
#pragma unroll
    for (int j = 0; j < 8; j++) {
      float q = bf2f((ushort)qv[j]);
      au[j] = (short)f2bf(q + up[j]);
      av[j] = (short)f2bf(q + vp[j]);
    }
    afu[kst] = au; afv[kst] = av;
  }

  const int jb = 256 + i0;
  const int smax = 2303 - i0;
  const int sbase = wave * 16;

  auto produce = [&](int r0, bf16x8 rf0, bf16x8 rf1) {
    f32x4 acc = {};
    __builtin_amdgcn_s_setprio(1);
    acc = __builtin_amdgcn_mfma_f32_16x16x32_bf16(afv[0], rf0, acc, 0, 0, 0);
    acc = __builtin_amdgcn_mfma_f32_16x16x32_bf16(afv[1], rf1, acc, 0, 0, 0);
    __builtin_amdgcn_s_setprio(0);
#pragma unroll
    for (int rr = 0; rr < 4; rr++)
      ring[wave][g * 4 + rr][(r0 + fr) & 63] = f2bf(acc[rr]);
  };
  auto loadRrow = [&](int row, bf16x8* out0, bf16x8* out1) {
    const int rc = row < 0 ? 0 : row;
    *out0 = *(const bf16x8*)(Rb + (size_t)rc * D_ + hD + g * 8);
    *out1 = *(const bf16x8*)(Rb + (size_t)rc * D_ + hD + 32 + g * 8);
  };
  auto loadK = [&](int ch, bf16x8 (&kp)[2][2]) {
#pragma unroll
    for (int half = 0; half < 2; half++) {
      const int sa = sbase + ch * 32 + half * 16 + fr;
      const int jc = (jb + sa < L_ - 1) ? (jb + sa) : (L_ - 1);
      kp[half][0] = *(const bf16x8*)(kb + (size_t)jc * 1024 + hD + g * 8);
      kp[half][1] = *(const bf16x8*)(kb + (size_t)jc * 1024 + hD + 32 + g * 8);
    }
  };
  auto loadV = [&](int ch, bf16x8 (&vp)[4]) {
    int kc = jb + sbase + ch * 32 + g * 8;
    if (kc > L_ - 8) kc = L_ - 8;
#pragma unroll
    for (int n = 0; n < 4; n++)
      vp[n] = *(const bf16x8*)(Vt + (size_t)(hD + n * 16 + fr) * L_ + kc);
  };

#pragma unroll
  for (int t = 0; t < 3; t++) {
    const int r0 = 480 + t * 16;
    bf16x8 rf0, rf1;
    loadRrow(r0 + fr, &rf0, &rf1);
    produce(r0, rf0, rf1);
  }

  float m4[4], l4[4];
  f32x4 oacc[4] = {};
#pragma unroll
  for (int rr = 0; rr < 4; rr++) { m4[rr] = -1e30f; l4[rr] = 0.f; }

  bf16x8 kA[2][2], vA[4], kB[2][2], vB[4];
  bf16x8 rP0a, rP0b, rP1a, rP1b;
  loadK(0, kA); loadV(0, vA);

  auto body = [&](int ch, bf16x8 (&kU)[2][2], bf16x8 (&vU)[4],
                  bf16x8 (&kP)[2][2], bf16x8 (&vP)[4], bool first) -> bool {
    const int c0 = sbase + ch * 32;
    if (c0 > smax) return false;
    if (!first) {
      const int r0 = 480 - ch * 32;
      produce(r0, rP0a, rP0b);
      produce(r0 + 16, rP1a, rP1b);
    }
    if (ch < 16) {
      const int r0n = 480 - (ch + 1) * 32;
      loadRrow(r0n + fr, &rP0a, &rP0b);
      loadRrow(r0n + 16 + fr, &rP1a, &rP1b);
      loadK(ch + 1, kP);
      loadV(ch + 1, vP);
    }
    f32x4 sc[2];
#pragma unroll
    for (int half = 0; half < 2; half++) {
      f32x4 acc = {};
      __builtin_amdgcn_s_setprio(1);
      acc = __builtin_amdgcn_mfma_f32_16x16x32_bf16(afu[0], kU[half][0], acc, 0, 0, 0);
      acc = __builtin_amdgcn_mfma_f32_16x16x32_bf16(afu[1], kU[half][1], acc, 0, 0, 0);
      __builtin_amdgcn_s_setprio(0);
      const int rb2 = 512 + g * 4 - (ch * 32 + half * 16 + fr);
      const int sa = c0 + half * 16 + fr;
#pragma unroll
      for (int rr = 0; rr < 4; rr++) {
        const int r = rb2 + rr;
        const float bd = bf2f(ring[wave][g * 4 + rr][r & 63]);
        const bool valid = ((unsigned)r <= 512u) && (sa <= smax);
        sc[half][rr] = valid ? (acc[rr] + bd) * 0.125f : -1e30f;
      }
    }
    if (first) {
      f32x4 cm;
#pragma unroll
      for (int rr = 0; rr < 4; rr++) cm[rr] = fmaxf(sc[0][rr], sc[1][rr]);
#pragma unroll
      for (int off = 8; off; off >>= 1)
#pragma unroll
        for (int rr = 0; rr < 4; rr++) cm[rr] = fmaxf(cm[rr], __shfl_xor(cm[rr], off));
#pragma unroll
      for (int rr = 0; rr < 4; rr++) m4[rr] = cm[rr];
    } else {
      bool rise = false;
#pragma unroll
      for (int rr = 0; rr < 4; rr++)
        rise |= (fmaxf(sc[0][rr], sc[1][rr]) > m4[rr] + 8.f);
      if (__any(rise)) {
        f32x4 cm;
#pragma unroll
        for (int rr = 0; rr < 4; rr++) cm[rr] = fmaxf(sc[0][rr], sc[1][rr]);
#pragma unroll
        for (int off = 8; off; off >>= 1)
#pragma unroll
          for (int rr = 0; rr < 4; rr++) cm[rr] = fmaxf(cm[rr], __shfl_xor(cm[rr], off));
#pragma unroll
        for (int rr = 0; rr < 4; rr++) {
          const float nm = fmaxf(m4[rr], cm[rr]);
          const float esc = __expf(m4[rr] - nm);
          m4[rr] = nm;
          l4[rr] *= esc;
#pragma unroll
          for (int n = 0; n < 4; n++) oacc[n][rr] *= esc;
        }
      }
    }
    f32x4 pA, pB;
#pragma unroll
    for (int rr = 0; rr < 4; rr++) {
      pA[rr] = __expf(sc[0][rr] - m4[rr]);
      pB[rr] = __expf(sc[1][rr] - m4[rr]);
      l4[rr] += pA[rr] + pB[rr];
    }
#pragma unroll
    for (int rr = 0; rr < 4; rr++) {
      Pl[wave][g * 4 + rr][fr]      = f2bf(pA[rr]);
      Pl[wave][g * 4 + rr][16 + fr] = f2bf(pB[rr]);
    }
    bf16x8 pf = *(const bf16x8*)&Pl[wave][fr][g * 8];
    __builtin_amdgcn_s_setprio(1);
#pragma unroll
    for (int n = 0; n < 4; n++)
      oacc[n] = __builtin_amdgcn_mfma_f32_16x16x32_bf16(pf, vU[n], oacc[n], 0, 0, 0);
    __builtin_amdgcn_s_setprio(0);
    return true;
  };

  bool cont = body(0, kA, vA, kB, vB, true);
  for (int ch = 1; ch < 17 && cont; ch += 2) {
    cont = body(ch, kB, vB, kA, vA, false);
    if (!cont || ch + 1 >= 17) break;
    cont = body(ch + 1, kA, vA, kB, vB, false);
  }

#pragma unroll
  for (int off = 8; off; off >>= 1)
#pragma unroll
    for (int rr = 0; rr < 4; rr++) l4[rr] += __shfl_xor(l4[rr], off);
#pragma unroll
  for (int rr = 0; rr < 4; rr++) {
    const float inv = 1.f / l4[rr];
    const size_t rowo = (size_t)(i0 + sbase + g * 4 + rr) * D_ + hD;
#pragma unroll
    for (int n = 0; n < 4; n++)
      attb[rowo + n * 16 + fr] = f2bf(oacc[n][rr] * inv);
  }
}

// ---------------- residual + LayerNorm (2 or 3 addends) ----------------
__global__ __launch_bounds__(256)
void ln_kernel(const float* __restrict__ a, const float* __restrict__ b,
               const float* __restrict__ c,
               const float* __restrict__ gamma, const float* __restrict__ beta,
               float* __restrict__ outf, ushort* __restrict__ outb) {
  const int row = blockIdx.x;
  const int tid = threadIdx.x;
  const int wave = tid >> 6, lane = tid & 63;
  float4 va = ((const float4*)(a + (size_t)row * D_))[tid];
  float4 vb4 = ((const float4*)(b + (size_t)row * D_))[tid];
  float4 xv;
  xv.x = va.x + vb4.x; xv.y = va.y + vb4.y; xv.z = va.z + vb4.z; xv.w = va.w + vb4.w;
  if (c) {
    float4 vc = ((const float4*)(c + (size_t)row * D_))[tid];
    xv.x += vc.x; xv.y += vc.y; xv.z += vc.z; xv.w += vc.w;
  }
  float s = xv.x + xv.y + xv.z + xv.w;
  float q = xv.x * xv.x + xv.y * xv.y + xv.z * xv.z + xv.w * xv.w;
#pragma unroll
  for (int off = 32; off; off >>= 1) { s += __shfl_xor(s, off); q += __shfl_xor(q, off); }
  __shared__ float red[8];
  if (lane == 0) { red[wave * 2] = s; red[wave * 2 + 1] = q; }
  __syncthreads();
  float ts = red[0] + red[2] + red[4] + red[6];
  float tq = red[1] + red[3] + red[5] + red[7];
  float mu = ts * (1.f / D_);
  float var = tq * (1.f / D_) - mu * mu;
  float rs = rsqrtf(var + 1e-5f);
  float4 g4 = ((const float4*)gamma)[tid];
  float4 be4 = ((const float4*)beta)[tid];
  float4 y;
  y.x = (xv.x - mu) * rs * g4.x + be4.x;
  y.y = (xv.y - mu) * rs * g4.y + be4.y;
  y.z = (xv.z - mu) * rs * g4.z + be4.z;
  y.w = (xv.w - mu) * rs * g4.w + be4.w;
  ((float4*)(outf + (size_t)row * D_))[tid] = y;
  if (outb) ((ushort4*)(outb + (size_t)row * D_))[tid] = pack4(y);
}

extern "C" void kernel_launch(void* const* d_in, const int* in_sizes, int n_in,
                              void* d_out, int out_size, void* d_ws, size_t ws_size,
                              hipStream_t stream) {
  const float* x    = (const float*)d_in[0];
  const float* mem  = (const float*)d_in[1];
  const float* Wq   = (const float*)d_in[2];
  const float* Wk   = (const float*)d_in[3];
  const float* Wv   = (const float*)d_in[4];
  const float* Wo   = (const float*)d_in[5];
  const float* Wr   = (const float*)d_in[6];
  const float* u    = (const float*)d_in[7];
  const float* v    = (const float*)d_in[8];
  const float* ln1g = (const float*)d_in[9];
  const float* ln1b = (const float*)d_in[10];
  const float* W1   = (const float*)d_in[11];
  const float* b1   = (const float*)d_in[12];
  const float* W2   = (const float*)d_in[13];
  const float* b2   = (const float*)d_in[14];
  const float* ln2g = (const float*)d_in[15];
  const float* ln2b = (const float*)d_in[16];
  float* out = (float*)d_out;

  char* ws = (char*)d_ws;
  size_t off = 0;
  auto take = [&](size_t n) { char* p = ws + off; off += (n + 255) & ~(size_t)255; return p; };

  ushort* WqT = (ushort*)take(2097152);
  ushort* WkT = (ushort*)take(2097152);   // WkT||WvT contiguous = [2048][1024]
  ushort* WvT = (ushort*)take(2097152);
  ushort* WoT = (ushort*)take(2097152);
  ushort* WrT = (ushort*)take(2097152);
  ushort* W1T = (ushort*)take(8388608);   // [4096][1024]
  ushort* W2T = (ushort*)take(8388608);   // [1024][4096]

  char* regA = take(8388608);             // kvb + remb; later reused for fbuf
  ushort* kvb  = (ushort*)regA;
  ushort* remb = (ushort*)(regA + 5242880);
  float*  fbuf = (float*)regA;

  char* regB = take(20185088);            // qb,kb,Vt,Rb,attb; overlays: o2b, g
  ushort* qb   = (ushort*)regB;
  ushort* kb   = (ushort*)(regB + 4194304);
  ushort* Vt   = (ushort*)(regB + 9437184);           // [1024][2560]
  ushort* Rb   = (ushort*)(regB + 14680064);
  ushort* attb = (ushort*)(regB + 15990784);
  float*  o2b  = (float*)regB;
  ushort* g    = (ushort*)regB;

  float*  o2 = (float*)take(8388608);
  float*  h  = (float*)take(8388608);
  ushort* hb = (ushort*)take(4194304);

  prep_kernel<<<17152, 256, 0, stream>>>(x, mem, Wq, Wk, Wv, Wo, Wr, W1, W2,
                                         WqT, WkT, WvT, WoT, WrT, W1T, W2T, kvb, remb);

  proj_gemm<<<1952, 256, 0, stream>>>(kvb, WqT, WkT, WrT, remb, qb, kb, Vt, Rb);

  attn_mfma4<<<512, 256, 0, stream>>>(qb, kb, Vt, Rb, u, v, attb);

  gemm_kern<64, 64, 1, 2><<<dim3(1024), 256, 0, stream>>>(attb, WoT, o2, o2b, nullptr,
                                                          2048, 1024, 512, 1024, 16);
  ln_kernel<<<2048, 256, 0, stream>>>(x, o2, o2b, ln1g, ln1b, h, hb);
  gemm_kern<64, 64, 2, 1><<<dim3(2048), 256, 0, stream>>>(hb, W1T, g, nullptr, b1,
                                                          2048, 4096, 1024, 1024, 64);
  gemm_kern<64, 64, 3, 2><<<dim3(1024), 256, 0, stream>>>(g, W2T, fbuf, o2, b2,
                                                          2048, 1024, 2048, 4096, 16);
  ln_kernel<<<2048, 256, 0, stream>>>(h, fbuf, o2, ln2g, ln2b, out, nullptr);
}

// Round 10
// 274.545 us; speedup vs baseline: 1.0856x; 1.0856x over previous
//
#include <hip/hip_runtime.h>
#include <hip/hip_bf16.h>
#include <cstdint>

#define S_ 2048
#define M_ 512
#define L_ 2560
#define D_ 1024
#define F_ 4096
#define H_ 16
#define DH_ 64
#define W_ 256
#define NR_ 513
#define NRP_ 640

typedef unsigned int uint32;
typedef __attribute__((ext_vector_type(8))) short bf16x8;
typedef __attribute__((ext_vector_type(4))) float f32x4;

__device__ __forceinline__ ushort f2bf(float f) {
  uint32 u = __builtin_bit_cast(uint32, f);
  u += 0x7FFFu + ((u >> 16) & 1u);
  return (ushort)(u >> 16);
}
__device__ __forceinline__ float bf2f(ushort s) {
  uint32 u = ((uint32)s) << 16;
  return __builtin_bit_cast(float, u);
}
__device__ __forceinline__ ushort4 pack4(float4 vf) {
  ushort4 r;
  r.x = f2bf(vf.x); r.y = f2bf(vf.y); r.z = f2bf(vf.z); r.w = f2bf(vf.w);
  return r;
}
__device__ __forceinline__ float gelu_tanh(float x) {
  float t = 0.7978845608028654f * x * (1.f + 0.044715f * x * x);
  float e = __expf(2.f * t);
  float th = 1.f - 2.f / (e + 1.f);
  return 0.5f * x * (1.f + th);
}

// async global(16B/lane) -> LDS, wave-uniform LDS base + lane*16
__device__ __forceinline__ void gld_lds16(const ushort* g, ushort* l) {
  __builtin_amdgcn_global_load_lds((const __attribute__((address_space(1))) void*)g,
                                   (__attribute__((address_space(3))) void*)l, 16, 0, 0);
}

// ================= fused prep: 7 weight transposes + kv pack + sinusoid =================
__device__ __forceinline__ void tr_tile(const float* __restrict__ in, ushort* __restrict__ out,
                                        int R, int C, int c0, int r0, int tx, int ty,
                                        float (*tile)[33]) {
#pragma unroll
  for (int i = 0; i < 4; i++)
    tile[ty + i * 8][tx] = in[(size_t)(r0 + ty + i * 8) * C + c0 + tx];
  __syncthreads();
#pragma unroll
  for (int i = 0; i < 4; i++)
    out[(size_t)(c0 + ty + i * 8) * R + r0 + tx] = f2bf(tile[tx][ty + i * 8]);
}

__global__ __launch_bounds__(256)
void prep_kernel(const float* __restrict__ x, const float* __restrict__ mem,
                 const float* __restrict__ Wq, const float* __restrict__ Wk,
                 const float* __restrict__ Wv, const float* __restrict__ Wo,
                 const float* __restrict__ Wr, const float* __restrict__ W1,
                 const float* __restrict__ W2,
                 ushort* __restrict__ WqT, ushort* __restrict__ WkT,
                 ushort* __restrict__ WvT, ushort* __restrict__ WoT,
                 ushort* __restrict__ WrT, ushort* __restrict__ W1T,
                 ushort* __restrict__ W2T,
                 ushort* __restrict__ kvb, ushort* __restrict__ remb) {
  __shared__ float tile[32][33];
  const int bid = blockIdx.x;
  const int tid = threadIdx.x;
  const int tx = tid & 31, ty = tid >> 5;

  if (bid < 5120) {
    const int which = bid >> 10, idx = bid & 1023;
    const float* ins[5] = {Wq, Wk, Wv, Wo, Wr};
    ushort* outs[5] = {WqT, WkT, WvT, WoT, WrT};
    tr_tile(ins[which], outs[which], 1024, 1024, (idx & 31) * 32, (idx >> 5) * 32, tx, ty, tile);
  } else if (bid < 9216) {
    const int idx = bid - 5120;
    tr_tile(W1, W1T, 1024, 4096, (idx % 128) * 32, (idx / 128) * 32, tx, ty, tile);
  } else if (bid < 13312) {
    const int idx = bid - 9216;
    tr_tile(W2, W2T, 4096, 1024, (idx & 31) * 32, (idx >> 5) * 32, tx, ty, tile);
  } else if (bid < 15872) {
    const int k = (bid - 13312) * 256 + tid;
    const int l = k >> 8, c = k & 255;
    const float4* src = (l < M_) ? (const float4*)(mem + (size_t)l * D_)
                                 : (const float4*)(x + (size_t)(l - M_) * D_);
    ((ushort4*)kvb)[k] = pack4(src[c]);
  } else {
    const int idx = (bid - 15872) * 256 + tid;
    const int r = idx >> 9, f = idx & 511;
    if (r < NR_) {
      float invf = expf(-(float)f * (9.210340371976184f / 512.0f));
      float ang = (float)(r - W_) * invf;
      remb[(size_t)r * D_ + f] = f2bf(sinf(ang));
      remb[(size_t)r * D_ + 512 + f] = f2bf(cosf(ang));
    } else if (r < NRP_) {
      remb[(size_t)r * D_ + f] = 0;
      remb[(size_t)r * D_ + 512 + f] = 0;
    }
  }
}

// ====== MFMA GEMM core: BK=64, 2-phase, BM x BN tiles ======
// C[M,N] = A[M,K] x BT[N,K]^T, bf16 in. 1D grid with XCD-bijective swizzle.
// EPI: 0 bf16; 1 f32 (SPLITK: z>0 -> partials, no bias); 2 bf16(gelu(c+bias));
//      3 f32(c+bias) (SPLITK: z>0 -> partials, no bias); 5 split kb/Vt.
template <int BM, int BN, int EPI, int SPLITK>
__device__ __forceinline__
void gemm_core(const ushort* __restrict__ A, const ushort* __restrict__ BT,
               void* __restrict__ Cout, void* __restrict__ Cout2,
               void* __restrict__ Cout3, void* __restrict__ Cout4,
               const float* __restrict__ bias, int Msz, int Nsz, int Ksz, int Kstride,
               int gx, int bid, int nwg, ushort* smem) {
  constexpr int PA = BM * 8 + 16;       // halfwords per kg-block
  constexpr int PB = BN * 8 + 16;
  constexpr int MFR = BM / 32;
  constexpr int NFR = BN / 32;
  constexpr int NAI = (BM / 64) * 8;    // A stage insts per block per tile
  constexpr int NBI = (BN / 64) * 8;
  constexpr int NPW = (NAI + NBI) / 4;  // stage insts per thread
  const int tid = threadIdx.x;
  const int wave = tid >> 6, lane = tid & 63;
  const int wr = wave >> 1, wc = wave & 1;

  const int q = nwg >> 3;
  const int swz = (bid & 7) * q + (bid >> 3);
  const int gy = Msz / BM;
  const int bx = swz % gx;
  const int rest = swz / gx;
  const int by = rest % gy;
  const int bz = rest / gy;

  const int brow = by * BM, bcol = bx * BN;
  const int koff = (SPLITK > 1) ? bz * Ksz : 0;

  ushort* As = smem;                    // 2 bufs x 8*PA
  ushort* Bs = smem + 2 * 8 * PA;       // 2 bufs x 8*PB

  const ushort* gsrc[NPW]; int ldst[NPW];
#pragma unroll
  for (int i = 0; i < NPW; i++) {
    const int idx = i * 4 + wave;
    if (i < NAI / 4) {
      const int rowbase = (idx >> 3) * 64, kg = idx & 7;
      gsrc[i] = A + (size_t)(brow + rowbase + lane) * Kstride + koff + kg * 8;
      ldst[i] = kg * PA + rowbase * 8;
    } else {
      const int b = idx - NAI;
      const int rowbase = (b >> 3) * 64, kg = b & 7;
      gsrc[i] = BT + (size_t)(bcol + rowbase + lane) * Kstride + koff + kg * 8;
      ldst[i] = kg * PB + rowbase * 8;
    }
  }

  f32x4 acc[MFR][NFR] = {};
  const int kgf = lane >> 4, fr = lane & 15;
  const int nk = Ksz >> 6;              // BK = 64

  auto stage = [&](int t, int buf) {
    const int ko = t * 64;
    ushort* ab = As + buf * 8 * PA;
    ushort* bb = Bs + buf * 8 * PB;
#pragma unroll
    for (int i = 0; i < NPW; i++) {
      ushort* base = (i < NAI / 4) ? ab : bb;
      gld_lds16(gsrc[i] + ko, base + ldst[i]);
    }
  };

  stage(0, 0);
  asm volatile("s_waitcnt vmcnt(0)" ::: "memory");
  __builtin_amdgcn_s_barrier();
  __builtin_amdgcn_sched_barrier(0);

  int cur = 0;
  for (int t = 0; t < nk; t++) {
    if (t + 1 < nk) stage(t + 1, cur ^ 1);   // issue next-tile loads FIRST
    ushort* ab = As + cur * 8 * PA;
    ushort* bb = Bs + cur * 8 * PB;
#pragma unroll
    for (int kk = 0; kk < 2; kk++) {
      bf16x8 af[MFR], bfv[NFR];
#pragma unroll
      for (int m = 0; m < MFR; m++)
        af[m] = *(const bf16x8*)(ab + (kk * 4 + kgf) * PA + (wr * (BM / 2) + m * 16 + fr) * 8);
#pragma unroll
      for (int n = 0; n < NFR; n++)
        bfv[n] = *(const bf16x8*)(bb + (kk * 4 + kgf) * PB + (wc * (BN / 2) + n * 16 + fr) * 8);
#pragma unroll
      for (int m = 0; m < MFR; m++)
#pragma unroll
        for (int n = 0; n < NFR; n++)
          acc[m][n] = __builtin_amdgcn_mfma_f32_16x16x32_bf16(af[m], bfv[n], acc[m][n], 0, 0, 0);
    }
    if (t + 1 < nk) {
      asm volatile("s_waitcnt vmcnt(0)" ::: "memory");
      __builtin_amdgcn_s_barrier();
      __builtin_amdgcn_sched_barrier(0);
    }
    cur ^= 1;
  }

  const int r4 = (lane >> 4) * 4;
  float* co = (float*)Cout;
  bool addb = (EPI == 3);
  if constexpr (SPLITK >= 2) {
    if (bz == 1) { co = (float*)Cout2; addb = false; }
    if constexpr (SPLITK == 4) {
      if (bz == 2) { co = (float*)Cout3; addb = false; }
      if (bz == 3) { co = (float*)Cout4; addb = false; }
    }
  }
#pragma unroll
  for (int m = 0; m < MFR; m++) {
#pragma unroll
    for (int n = 0; n < NFR; n++) {
      const int col = bcol + wc * (BN / 2) + n * 16 + fr;
      if constexpr (EPI == 5) {
        if (col < 1024) {
#pragma unroll
          for (int r = 0; r < 4; r++) {
            const int row = brow + wr * (BM / 2) + m * 16 + r4 + r;
            ((ushort*)Cout)[(size_t)row * 1024 + col] = f2bf(acc[m][n][r]);
          }
        } else {
          const int row0 = brow + wr * (BM / 2) + m * 16 + r4;
          ushort4 pk;
          pk.x = f2bf(acc[m][n][0]); pk.y = f2bf(acc[m][n][1]);
          pk.z = f2bf(acc[m][n][2]); pk.w = f2bf(acc[m][n][3]);
          *(ushort4*)((ushort*)Cout2 + (size_t)(col - 1024) * Msz + row0) = pk;
        }
      } else {
#pragma unroll
        for (int r = 0; r < 4; r++) {
          const int row = brow + wr * (BM / 2) + m * 16 + r4 + r;
          float val = acc[m][n][r];
          size_t o = (size_t)row * Nsz + col;
          if constexpr (EPI == 0) ((ushort*)Cout)[o] = f2bf(val);
          else if constexpr (EPI == 2) ((ushort*)Cout)[o] = f2bf(gelu_tanh(val + bias[col]));
          else co[o] = addb ? val + bias[col] : val;
        }
      }
    }
  }
}

template <int BM, int BN, int EPI, int SPLITK>
__global__ __launch_bounds__(256)
void gemm_kern(const ushort* __restrict__ A, const ushort* __restrict__ BT,
               void* __restrict__ Cout, void* __restrict__ Cout2,
               void* __restrict__ Cout3, void* __restrict__ Cout4,
               const float* __restrict__ bias, int Msz, int Nsz, int Ksz, int Kstride,
               int gx) {
  constexpr int PA = BM * 8 + 16, PB = BN * 8 + 16;
  __shared__ __align__(16) ushort smem[2 * 8 * (PA + PB)];
  gemm_core<BM, BN, EPI, SPLITK>(A, BT, Cout, Cout2, Cout3, Cout4, bias,
                                 Msz, Nsz, Ksz, Kstride, gx, blockIdx.x, gridDim.x, smem);
}

// merged Q / KV / R projection: 256 + 640 + 80 = 976 blocks (BM=64, BN=128)
__global__ __launch_bounds__(256)
void proj_gemm(const ushort* __restrict__ kvb, const ushort* __restrict__ WqT,
               const ushort* __restrict__ WkvT, const ushort* __restrict__ WrT,
               const ushort* __restrict__ remb,
               ushort* __restrict__ qb, ushort* __restrict__ kb,
               ushort* __restrict__ Vt, ushort* __restrict__ Rb) {
  __shared__ __align__(16) ushort smem[2 * 8 * (64 * 8 + 16 + 128 * 8 + 16)];
  const int bid = blockIdx.x;
  if (bid < 256) {
    gemm_core<64, 128, 0, 1>(kvb + 512 * 1024, WqT, qb, nullptr, nullptr, nullptr, nullptr,
                             2048, 1024, 1024, 1024, 8, bid, 256, smem);
  } else if (bid < 896) {
    gemm_core<64, 128, 5, 1>(kvb, WkvT, kb, Vt, nullptr, nullptr, nullptr,
                             2560, 2048, 1024, 1024, 16, bid - 256, 640, smem);
  } else {
    gemm_core<64, 128, 0, 1>(remb, WrT, Rb, nullptr, nullptr, nullptr, nullptr,
                             640, 1024, 1024, 1024, 8, bid - 896, 80, smem);
  }
}

// ---------------- banded attention v6: lazy-max, per-lane partial l, setprio ----------
__global__ __launch_bounds__(256)
void attn_mfma4(const ushort* __restrict__ qb, const ushort* __restrict__ kb,
                const ushort* __restrict__ Vt, const ushort* __restrict__ Rb,
                const float* __restrict__ ubias, const float* __restrict__ vbias,
                ushort* __restrict__ attb) {
  const int bid = blockIdx.x;
  const int swz = (bid & 7) * 64 + (bid >> 3);
  const int h = swz >> 5;
  const int i0 = (swz & 31) * 64;
  const int tid = threadIdx.x;
  const int wave = tid >> 6, lane = tid & 63;
  const int g = lane >> 4, fr = lane & 15;
  const int hD = h * DH_;

  __shared__ __align__(16) ushort ring[4][16][64];
  __shared__ __align__(16) ushort Pl[4][16][40];

  const int qi = i0 + wave * 16 + fr;
  bf16x8 afu[2], afv[2];
#pragma unroll
  for (int kst = 0; kst < 2; kst++) {
    const int dof = kst * 32 + g * 8;
    bf16x8 qv = *(const bf16x8*)(qb + (size_t)qi * D_ + hD + dof);
    const float* up = ubias + hD + dof;
    const float* vp = vbias + hD + dof;
    bf16x8 au, av;
#pragma unroll
    for (int j = 0; j < 8; j++) {
      float q = bf2f((ushort)qv[j]);
      au[j] = (short)f2bf(q + up[j]);
      av[j] = (short)f2bf(q + vp[j]);
    }
    afu[kst] = au; afv[kst] = av;
  }

  const int jb = 256 + i0;
  const int smax = 2303 - i0;
  const int sbase = wave * 16;

  auto produce = [&](int r0, bf16x8 rf0, bf16x8 rf1) {
    f32x4 acc = {};
    __builtin_amdgcn_s_setprio(1);
    acc = __builtin_amdgcn_mfma_f32_16x16x32_bf16(afv[0], rf0, acc, 0, 0, 0);
    acc = __builtin_amdgcn_mfma_f32_16x16x32_bf16(afv[1], rf1, acc, 0, 0, 0);
    __builtin_amdgcn_s_setprio(0);
#pragma unroll
    for (int rr = 0; rr < 4; rr++)
      ring[wave][g * 4 + rr][(r0 + fr) & 63] = f2bf(acc[rr]);
  };
  auto loadRrow = [&](int row, bf16x8* out0, bf16x8* out1) {
    const int rc = row < 0 ? 0 : row;
    *out0 = *(const bf16x8*)(Rb + (size_t)rc * D_ + hD + g * 8);
    *out1 = *(const bf16x8*)(Rb + (size_t)rc * D_ + hD + 32 + g * 8);
  };
  auto loadK = [&](int ch, bf16x8 (&kp)[2][2]) {
#pragma unroll
    for (int half = 0; half < 2; half++) {
      const int sa = sbase + ch * 32 + half * 16 + fr;
      const int jc = (jb + sa < L_ - 1) ? (jb + sa) : (L_ - 1);
      kp[half][0] = *(const bf16x8*)(kb + (size_t)jc * 1024 + hD + g * 8);
      kp[half][1] = *(const bf16x8*)(kb + (size_t)jc * 1024 + hD + 32 + g * 8);
    }
  };
  auto loadV = [&](int ch, bf16x8 (&vp)[4]) {
    int kc = jb + sbase + ch * 32 + g * 8;
    if (kc > L_ - 8) kc = L_ - 8;
#pragma unroll
    for (int n = 0; n < 4; n++)
      vp[n] = *(const bf16x8*)(Vt + (size_t)(hD + n * 16 + fr) * L_ + kc);
  };

#pragma unroll
  for (int t = 0; t < 3; t++) {
    const int r0 = 480 + t * 16;
    bf16x8 rf0, rf1;
    loadRrow(r0 + fr, &rf0, &rf1);
    produce(r0, rf0, rf1);
  }

  float m4[4], l4[4];
  f32x4 oacc[4] = {};
#pragma unroll
  for (int rr = 0; rr < 4; rr++) { m4[rr] = -1e30f; l4[rr] = 0.f; }

  bf16x8 kA[2][2], vA[4], kB[2][2], vB[4];
  bf16x8 rP0a, rP0b, rP1a, rP1b;
  loadK(0, kA); loadV(0, vA);

  auto body = [&](int ch, bf16x8 (&kU)[2][2], bf16x8 (&vU)[4],
                  bf16x8 (&kP)[2][2], bf16x8 (&vP)[4], bool first) -> bool {
    const int c0 = sbase + ch * 32;
    if (c0 > smax) return false;
    if (!first) {
      const int r0 = 480 - ch * 32;
      produce(r0, rP0a, rP0b);
      produce(r0 + 16, rP1a, rP1b);
    }
    if (ch < 16) {
      const int r0n = 480 - (ch + 1) * 32;
      loadRrow(r0n + fr, &rP0a, &rP0b);
      loadRrow(r0n + 16 + fr, &rP1a, &rP1b);
      loadK(ch + 1, kP);
      loadV(ch + 1, vP);
    }
    f32x4 sc[2];
#pragma unroll
    for (int half = 0; half < 2; half++) {
      f32x4 acc = {};
      __builtin_amdgcn_s_setprio(1);
      acc = __builtin_amdgcn_mfma_f32_16x16x32_bf16(afu[0], kU[half][0], acc, 0, 0, 0);
      acc = __builtin_amdgcn_mfma_f32_16x16x32_bf16(afu[1], kU[half][1], acc, 0, 0, 0);
      __builtin_amdgcn_s_setprio(0);
      const int rb2 = 512 + g * 4 - (ch * 32 + half * 16 + fr);
      const int sa = c0 + half * 16 + fr;
#pragma unroll
      for (int rr = 0; rr < 4; rr++) {
        const int r = rb2 + rr;
        const float bd = bf2f(ring[wave][g * 4 + rr][r & 63]);
        const bool valid = ((unsigned)r <= 512u) && (sa <= smax);
        sc[half][rr] = valid ? (acc[rr] + bd) * 0.125f : -1e30f;
      }
    }
    if (first) {
      f32x4 cm;
#pragma unroll
      for (int rr = 0; rr < 4; rr++) cm[rr] = fmaxf(sc[0][rr], sc[1][rr]);
#pragma unroll
      for (int off = 8; off; off >>= 1)
#pragma unroll
        for (int rr = 0; rr < 4; rr++) cm[rr] = fmaxf(cm[rr], __shfl_xor(cm[rr], off));
#pragma unroll
      for (int rr = 0; rr < 4; rr++) m4[rr] = cm[rr];
    } else {
      bool rise = false;
#pragma unroll
      for (int rr = 0; rr < 4; rr++)
        rise |= (fmaxf(sc[0][rr], sc[1][rr]) > m4[rr] + 8.f);
      if (__any(rise)) {
        f32x4 cm;
#pragma unroll
        for (int rr = 0; rr < 4; rr++) cm[rr] = fmaxf(sc[0][rr], sc[1][rr]);
#pragma unroll
        for (int off = 8; off; off >>= 1)
#pragma unroll
          for (int rr = 0; rr < 4; rr++) cm[rr] = fmaxf(cm[rr], __shfl_xor(cm[rr], off));
#pragma unroll
        for (int rr = 0; rr < 4; rr++) {
          const float nm = fmaxf(m4[rr], cm[rr]);
          const float esc = __expf(m4[rr] - nm);
          m4[rr] = nm;
          l4[rr] *= esc;
#pragma unroll
          for (int n = 0; n < 4; n++) oacc[n][rr] *= esc;
        }
      }
    }
    f32x4 pA, pB;
#pragma unroll
    for (int rr = 0; rr < 4; rr++) {
      pA[rr] = __expf(sc[0][rr] - m4[rr]);
      pB[rr] = __expf(sc[1][rr] - m4[rr]);
      l4[rr] += pA[rr] + pB[rr];
    }
#pragma unroll
    for (int rr = 0; rr < 4; rr++) {
      Pl[wave][g * 4 + rr][fr]      = f2bf(pA[rr]);
      Pl[wave][g * 4 + rr][16 + fr] = f2bf(pB[rr]);
    }
    bf16x8 pf = *(const bf16x8*)&Pl[wave][fr][g * 8];
    __builtin_amdgcn_s_setprio(1);
#pragma unroll
    for (int n = 0; n < 4; n++)
      oacc[n] = __builtin_amdgcn_mfma_f32_16x16x32_bf16(pf, vU[n], oacc[n], 0, 0, 0);
    __builtin_amdgcn_s_setprio(0);
    return true;
  };

  bool cont = body(0, kA, vA, kB, vB, true);
  for (int ch = 1; ch < 17 && cont; ch += 2) {
    cont = body(ch, kB, vB, kA, vA, false);
    if (!cont || ch + 1 >= 17) break;
    cont = body(ch + 1, kA, vA, kB, vB, false);
  }

#pragma unroll
  for (int off = 8; off; off >>= 1)
#pragma unroll
    for (int rr = 0; rr < 4; rr++) l4[rr] += __shfl_xor(l4[rr], off);
#pragma unroll
  for (int rr = 0; rr < 4; rr++) {
    const float inv = 1.f / l4[rr];
    const size_t rowo = (size_t)(i0 + sbase + g * 4 + rr) * D_ + hD;
#pragma unroll
    for (int n = 0; n < 4; n++)
      attb[rowo + n * 16 + fr] = f2bf(oacc[n][rr] * inv);
  }
}

// ---------------- residual + LayerNorm (2..5 addends) ----------------
__global__ __launch_bounds__(256)
void ln_kernel(const float* __restrict__ a, const float* __restrict__ b,
               const float* __restrict__ c, const float* __restrict__ d,
               const float* __restrict__ e,
               const float* __restrict__ gamma, const float* __restrict__ beta,
               float* __restrict__ outf, ushort* __restrict__ outb) {
  const int row = blockIdx.x;
  const int tid = threadIdx.x;
  const int wave = tid >> 6, lane = tid & 63;
  float4 va = ((const float4*)(a + (size_t)row * D_))[tid];
  float4 vb4 = ((const float4*)(b + (size_t)row * D_))[tid];
  float4 xv;
  xv.x = va.x + vb4.x; xv.y = va.y + vb4.y; xv.z = va.z + vb4.z; xv.w = va.w + vb4.w;
  if (c) {
    float4 vc = ((const float4*)(c + (size_t)row * D_))[tid];
    xv.x += vc.x; xv.y += vc.y; xv.z += vc.z; xv.w += vc.w;
  }
  if (d) {
    float4 vd = ((const float4*)(d + (size_t)row * D_))[tid];
    xv.x += vd.x; xv.y += vd.y; xv.z += vd.z; xv.w += vd.w;
  }
  if (e) {
    float4 ve = ((const float4*)(e + (size_t)row * D_))[tid];
    xv.x += ve.x; xv.y += ve.y; xv.z += ve.z; xv.w += ve.w;
  }
  float s = xv.x + xv.y + xv.z + xv.w;
  float q = xv.x * xv.x + xv.y * xv.y + xv.z * xv.z + xv.w * xv.w;
#pragma unroll
  for (int off = 32; off; off >>= 1) { s += __shfl_xor(s, off); q += __shfl_xor(q, off); }
  __shared__ float red[8];
  if (lane == 0) { red[wave * 2] = s; red[wave * 2 + 1] = q; }
  __syncthreads();
  float ts = red[0] + red[2] + red[4] + red[6];
  float tq = red[1] + red[3] + red[5] + red[7];
  float mu = ts * (1.f / D_);
  float var = tq * (1.f / D_) - mu * mu;
  float rs = rsqrtf(var + 1e-5f);
  float4 g4 = ((const float4*)gamma)[tid];
  float4 be4 = ((const float4*)beta)[tid];
  float4 y;
  y.x = (xv.x - mu) * rs * g4.x + be4.x;
  y.y = (xv.y - mu) * rs * g4.y + be4.y;
  y.z = (xv.z - mu) * rs * g4.z + be4.z;
  y.w = (xv.w - mu) * rs * g4.w + be4.w;
  ((float4*)(outf + (size_t)row * D_))[tid] = y;
  if (outb) ((ushort4*)(outb + (size_t)row * D_))[tid] = pack4(y);
}

extern "C" void kernel_launch(void* const* d_in, const int* in_sizes, int n_in,
                              void* d_out, int out_size, void* d_ws, size_t ws_size,
                              hipStream_t stream) {
  const float* x    = (const float*)d_in[0];
  const float* mem  = (const float*)d_in[1];
  const float* Wq   = (const float*)d_in[2];
  const float* Wk   = (const float*)d_in[3];
  const float* Wv   = (const float*)d_in[4];
  const float* Wo   = (const float*)d_in[5];
  const float* Wr   = (const float*)d_in[6];
  const float* u    = (const float*)d_in[7];
  const float* v    = (const float*)d_in[8];
  const float* ln1g = (const float*)d_in[9];
  const float* ln1b = (const float*)d_in[10];
  const float* W1   = (const float*)d_in[11];
  const float* b1   = (const float*)d_in[12];
  const float* W2   = (const float*)d_in[13];
  const float* b2   = (const float*)d_in[14];
  const float* ln2g = (const float*)d_in[15];
  const float* ln2b = (const float*)d_in[16];
  float* out = (float*)d_out;

  char* ws = (char*)d_ws;
  size_t off = 0;
  auto take = [&](size_t n) { char* p = ws + off; off += (n + 255) & ~(size_t)255; return p; };

  ushort* WqT = (ushort*)take(2097152);   // dead after proj -> FFN2 z2 partial (8MB spans WqT..WvT)
  ushort* WkT = (ushort*)take(2097152);   // WkT||WvT contiguous = [2048][1024]
  ushort* WvT = (ushort*)take(2097152);
  ushort* WoT = (ushort*)take(2097152);   // dead after Wo gemm
  ushort* WrT = (ushort*)take(2097152);
  ushort* W1T = (ushort*)take(8388608);   // [4096][1024]; dead after FFN1 -> FFN2 z3 partial
  ushort* W2T = (ushort*)take(8388608);   // [1024][4096]

  char* regA = take(8388608);             // kvb + remb; later reused for fbuf
  ushort* kvb  = (ushort*)regA;
  ushort* remb = (ushort*)(regA + 5242880);
  float*  fbuf = (float*)regA;            // FFN2 z0 (+bias)

  char* regB = take(20185088);            // qb,kb,Vt,Rb,attb; overlays: o2b, g
  ushort* qb   = (ushort*)regB;
  ushort* kb   = (ushort*)(regB + 4194304);
  ushort* Vt   = (ushort*)(regB + 9437184);           // [1024][2560]
  ushort* Rb   = (ushort*)(regB + 14680064);
  ushort* attb = (ushort*)(regB + 15990784);
  float*  o2b  = (float*)regB;                        // Wo z=1 partial
  ushort* g    = (ushort*)regB;                       // FFN1 out (16MB)

  float*  o2 = (float*)take(8388608);     // Wo z=0 partial; later FFN2 z1 partial
  float*  h  = (float*)take(8388608);
  ushort* hb = (ushort*)take(4194304);

  float* p2 = (float*)WqT;                // FFN2 z2 partial (WqT..WvT region, 8MB)
  float* p3 = (float*)W1T;                // FFN2 z3 partial (W1T region, 8MB)

  prep_kernel<<<17152, 256, 0, stream>>>(x, mem, Wq, Wk, Wv, Wo, Wr, W1, W2,
                                         WqT, WkT, WvT, WoT, WrT, W1T, W2T, kvb, remb);

  proj_gemm<<<976, 256, 0, stream>>>(kvb, WqT, WkT, WrT, remb, qb, kb, Vt, Rb);

  attn_mfma4<<<512, 256, 0, stream>>>(qb, kb, Vt, Rb, u, v, attb);

  gemm_kern<64, 128, 1, 2><<<512, 256, 0, stream>>>(attb, WoT, o2, o2b, nullptr, nullptr,
                                                    nullptr, 2048, 1024, 512, 1024, 8);
  ln_kernel<<<2048, 256, 0, stream>>>(x, o2, o2b, nullptr, nullptr, ln1g, ln1b, h, hb);
  gemm_kern<64, 128, 2, 1><<<1024, 256, 0, stream>>>(hb, W1T, g, nullptr, nullptr, nullptr,
                                                     b1, 2048, 4096, 1024, 1024, 32);
  gemm_kern<64, 128, 3, 4><<<1024, 256, 0, stream>>>(g, W2T, fbuf, o2, p2, p3,
                                                     b2, 2048, 1024, 1024, 4096, 8);
  ln_kernel<<<2048, 256, 0, stream>>>(h, fbuf, o2, p2, p3, ln2g, ln2b, out, nullptr);
}

// Round 11
// 252.617 us; speedup vs baseline: 1.1798x; 1.0868x over previous
//
#include <hip/hip_runtime.h>
#include <hip/hip_bf16.h>
#include <cstdint>

#define S_ 2048
#define M_ 512
#define L_ 2560
#define D_ 1024
#define F_ 4096
#define H_ 16
#define DH_ 64
#define W_ 256
#define NR_ 513
#define NRP_ 640

typedef unsigned int uint32;
typedef __attribute__((ext_vector_type(8))) short bf16x8;
typedef __attribute__((ext_vector_type(4))) float f32x4;

__device__ __forceinline__ ushort f2bf(float f) {
  uint32 u = __builtin_bit_cast(uint32, f);
  u += 0x7FFFu + ((u >> 16) & 1u);
  return (ushort)(u >> 16);
}
__device__ __forceinline__ float bf2f(ushort s) {
  uint32 u = ((uint32)s) << 16;
  return __builtin_bit_cast(float, u);
}
__device__ __forceinline__ ushort4 pack4(float4 vf) {
  ushort4 r;
  r.x = f2bf(vf.x); r.y = f2bf(vf.y); r.z = f2bf(vf.z); r.w = f2bf(vf.w);
  return r;
}
__device__ __forceinline__ float gelu_tanh(float x) {
  float t = 0.7978845608028654f * x * (1.f + 0.044715f * x * x);
  float e = __expf(2.f * t);
  float th = 1.f - 2.f / (e + 1.f);
  return 0.5f * x * (1.f + th);
}

// async global(16B/lane) -> LDS, wave-uniform LDS base + lane*16
__device__ __forceinline__ void gld_lds16(const ushort* g, ushort* l) {
  __builtin_amdgcn_global_load_lds((const __attribute__((address_space(1))) void*)g,
                                   (__attribute__((address_space(3))) void*)l, 16, 0, 0);
}

// ================= fused prep: 7 weight transposes + kv pack + sinusoid =================
__device__ __forceinline__ void tr_tile(const float* __restrict__ in, ushort* __restrict__ out,
                                        int R, int C, int c0, int r0, int tx, int ty,
                                        float (*tile)[33]) {
#pragma unroll
  for (int i = 0; i < 4; i++)
    tile[ty + i * 8][tx] = in[(size_t)(r0 + ty + i * 8) * C + c0 + tx];
  __syncthreads();
#pragma unroll
  for (int i = 0; i < 4; i++)
    out[(size_t)(c0 + ty + i * 8) * R + r0 + tx] = f2bf(tile[tx][ty + i * 8]);
}

__global__ __launch_bounds__(256)
void prep_kernel(const float* __restrict__ x, const float* __restrict__ mem,
                 const float* __restrict__ Wq, const float* __restrict__ Wk,
                 const float* __restrict__ Wv, const float* __restrict__ Wo,
                 const float* __restrict__ Wr, const float* __restrict__ W1,
                 const float* __restrict__ W2,
                 ushort* __restrict__ WqT, ushort* __restrict__ WkT,
                 ushort* __restrict__ WvT, ushort* __restrict__ WoT,
                 ushort* __restrict__ WrT, ushort* __restrict__ W1T,
                 ushort* __restrict__ W2T,
                 ushort* __restrict__ kvb, ushort* __restrict__ remb) {
  __shared__ float tile[32][33];
  const int bid = blockIdx.x;
  const int tid = threadIdx.x;
  const int tx = tid & 31, ty = tid >> 5;

  if (bid < 5120) {
    const int which = bid >> 10, idx = bid & 1023;
    const float* ins[5] = {Wq, Wk, Wv, Wo, Wr};
    ushort* outs[5] = {WqT, WkT, WvT, WoT, WrT};
    tr_tile(ins[which], outs[which], 1024, 1024, (idx & 31) * 32, (idx >> 5) * 32, tx, ty, tile);
  } else if (bid < 9216) {
    const int idx = bid - 5120;
    tr_tile(W1, W1T, 1024, 4096, (idx % 128) * 32, (idx / 128) * 32, tx, ty, tile);
  } else if (bid < 13312) {
    const int idx = bid - 9216;
    tr_tile(W2, W2T, 4096, 1024, (idx & 31) * 32, (idx >> 5) * 32, tx, ty, tile);
  } else if (bid < 15872) {
    const int k = (bid - 13312) * 256 + tid;
    const int l = k >> 8, c = k & 255;
    const float4* src = (l < M_) ? (const float4*)(mem + (size_t)l * D_)
                                 : (const float4*)(x + (size_t)(l - M_) * D_);
    ((ushort4*)kvb)[k] = pack4(src[c]);
  } else {
    const int idx = (bid - 15872) * 256 + tid;
    const int r = idx >> 9, f = idx & 511;
    if (r < NR_) {
      float invf = expf(-(float)f * (9.210340371976184f / 512.0f));
      float ang = (float)(r - W_) * invf;
      remb[(size_t)r * D_ + f] = f2bf(sinf(ang));
      remb[(size_t)r * D_ + 512 + f] = f2bf(cosf(ang));
    } else if (r < NRP_) {
      remb[(size_t)r * D_ + f] = 0;
      remb[(size_t)r * D_ + 512 + f] = 0;
    }
  }
}

// ====== 2-phase MFMA GEMM core (r8 config): BK=64, BM x 128 tiles ======
template <int BM, int BN, int EPI, int SPLITK>
__device__ __forceinline__
void gemm_core(const ushort* __restrict__ A, const ushort* __restrict__ BT,
               void* __restrict__ Cout, void* __restrict__ Cout2,
               const float* __restrict__ bias, int Msz, int Nsz, int Ksz, int Kstride,
               int gx, int bid, int nwg, ushort* smem) {
  constexpr int PA = BM * 8 + 16;
  constexpr int PB = BN * 8 + 16;
  constexpr int MFR = BM / 32;
  constexpr int NFR = BN / 32;
  constexpr int NAI = (BM / 64) * 8;
  constexpr int NBI = (BN / 64) * 8;
  constexpr int NPW = (NAI + NBI) / 4;
  const int tid = threadIdx.x;
  const int wave = tid >> 6, lane = tid & 63;
  const int wr = wave >> 1, wc = wave & 1;

  const int q = nwg >> 3;
  const int swz = (bid & 7) * q + (bid >> 3);
  const int gy = Msz / BM;
  const int bx = swz % gx;
  const int rest = swz / gx;
  const int by = rest % gy;
  const int bz = rest / gy;

  const int brow = by * BM, bcol = bx * BN;
  const int koff = (SPLITK > 1) ? bz * Ksz : 0;

  ushort* As = smem;
  ushort* Bs = smem + 2 * 8 * PA;

  const ushort* gsrc[NPW]; int ldst[NPW];
#pragma unroll
  for (int i = 0; i < NPW; i++) {
    const int idx = i * 4 + wave;
    if (i < NAI / 4) {
      const int rowbase = (idx >> 3) * 64, kg = idx & 7;
      gsrc[i] = A + (size_t)(brow + rowbase + lane) * Kstride + koff + kg * 8;
      ldst[i] = kg * PA + rowbase * 8;
    } else {
      const int b = idx - NAI;
      const int rowbase = (b >> 3) * 64, kg = b & 7;
      gsrc[i] = BT + (size_t)(bcol + rowbase + lane) * Kstride + koff + kg * 8;
      ldst[i] = kg * PB + rowbase * 8;
    }
  }

  f32x4 acc[MFR][NFR] = {};
  const int kgf = lane >> 4, fr = lane & 15;
  const int nk = Ksz >> 6;

  auto stage = [&](int t, int buf) {
    const int ko = t * 64;
    ushort* ab = As + buf * 8 * PA;
    ushort* bb = Bs + buf * 8 * PB;
#pragma unroll
    for (int i = 0; i < NPW; i++) {
      ushort* base = (i < NAI / 4) ? ab : bb;
      gld_lds16(gsrc[i] + ko, base + ldst[i]);
    }
  };

  stage(0, 0);
  asm volatile("s_waitcnt vmcnt(0)" ::: "memory");
  __builtin_amdgcn_s_barrier();
  __builtin_amdgcn_sched_barrier(0);

  int cur = 0;
  for (int t = 0; t < nk; t++) {
    if (t + 1 < nk) stage(t + 1, cur ^ 1);
    ushort* ab = As + cur * 8 * PA;
    ushort* bb = Bs + cur * 8 * PB;
#pragma unroll
    for (int kk = 0; kk < 2; kk++) {
      bf16x8 af[MFR], bfv[NFR];
#pragma unroll
      for (int m = 0; m < MFR; m++)
        af[m] = *(const bf16x8*)(ab + (kk * 4 + kgf) * PA + (wr * (BM / 2) + m * 16 + fr) * 8);
#pragma unroll
      for (int n = 0; n < NFR; n++)
        bfv[n] = *(const bf16x8*)(bb + (kk * 4 + kgf) * PB + (wc * (BN / 2) + n * 16 + fr) * 8);
#pragma unroll
      for (int m = 0; m < MFR; m++)
#pragma unroll
        for (int n = 0; n < NFR; n++)
          acc[m][n] = __builtin_amdgcn_mfma_f32_16x16x32_bf16(af[m], bfv[n], acc[m][n], 0, 0, 0);
    }
    if (t + 1 < nk) {
      asm volatile("s_waitcnt vmcnt(0)" ::: "memory");
      __builtin_amdgcn_s_barrier();
      __builtin_amdgcn_sched_barrier(0);
    }
    cur ^= 1;
  }

  const int r4 = (lane >> 4) * 4;
  float* co = (float*)Cout;
  bool addb = (EPI == 3);
  if constexpr (SPLITK == 2) {
    if (bz == 1) { co = (float*)Cout2; addb = false; }
  }
#pragma unroll
  for (int m = 0; m < MFR; m++) {
#pragma unroll
    for (int n = 0; n < NFR; n++) {
      const int col = bcol + wc * (BN / 2) + n * 16 + fr;
      if constexpr (EPI == 5) {
        if (col < 1024) {
#pragma unroll
          for (int r = 0; r < 4; r++) {
            const int row = brow + wr * (BM / 2) + m * 16 + r4 + r;
            ((ushort*)Cout)[(size_t)row * 1024 + col] = f2bf(acc[m][n][r]);
          }
        } else {
          const int row0 = brow + wr * (BM / 2) + m * 16 + r4;
          ushort4 pk;
          pk.x = f2bf(acc[m][n][0]); pk.y = f2bf(acc[m][n][1]);
          pk.z = f2bf(acc[m][n][2]); pk.w = f2bf(acc[m][n][3]);
          *(ushort4*)((ushort*)Cout2 + (size_t)(col - 1024) * Msz + row0) = pk;
        }
      } else {
#pragma unroll
        for (int r = 0; r < 4; r++) {
          const int row = brow + wr * (BM / 2) + m * 16 + r4 + r;
          float val = acc[m][n][r];
          size_t o = (size_t)row * Nsz + col;
          if constexpr (EPI == 0) ((ushort*)Cout)[o] = f2bf(val);
          else if constexpr (EPI == 2) ((ushort*)Cout)[o] = f2bf(gelu_tanh(val + bias[col]));
          else co[o] = addb ? val + bias[col] : val;
        }
      }
    }
  }
}

template <int BM, int BN, int EPI, int SPLITK>
__global__ __launch_bounds__(256)
void gemm_kern(const ushort* __restrict__ A, const ushort* __restrict__ BT,
               void* __restrict__ Cout, void* __restrict__ Cout2,
               const float* __restrict__ bias, int Msz, int Nsz, int Ksz, int Kstride,
               int gx) {
  constexpr int PA = BM * 8 + 16, PB = BN * 8 + 16;
  __shared__ __align__(16) ushort smem[2 * 8 * (PA + PB)];
  gemm_core<BM, BN, EPI, SPLITK>(A, BT, Cout, Cout2, bias, Msz, Nsz, Ksz, Kstride,
                                 gx, blockIdx.x, gridDim.x, smem);
}

// merged Q / KV / R projection: 256 + 640 + 80 = 976 blocks (BM=64, BN=128)
__global__ __launch_bounds__(256)
void proj_gemm(const ushort* __restrict__ kvb, const ushort* __restrict__ WqT,
               const ushort* __restrict__ WkvT, const ushort* __restrict__ WrT,
               const ushort* __restrict__ remb,
               ushort* __restrict__ qb, ushort* __restrict__ kb,
               ushort* __restrict__ Vt, ushort* __restrict__ Rb) {
  __shared__ __align__(16) ushort smem[2 * 8 * (64 * 8 + 16 + 128 * 8 + 16)];
  const int bid = blockIdx.x;
  if (bid < 256) {
    gemm_core<64, 128, 0, 1>(kvb + 512 * 1024, WqT, qb, nullptr, nullptr,
                             2048, 1024, 1024, 1024, 8, bid, 256, smem);
  } else if (bid < 896) {
    gemm_core<64, 128, 5, 1>(kvb, WkvT, kb, Vt, nullptr,
                             2560, 2048, 1024, 1024, 16, bid - 256, 640, smem);
  } else {
    gemm_core<64, 128, 0, 1>(remb, WrT, Rb, nullptr, nullptr,
                             640, 1024, 1024, 1024, 8, bid - 896, 80, smem);
  }
}

// ====== 8-phase 256x256 GEMM (T2+T3+T4+T5), strict half-tile pipeline ======
// 8 waves (512 thr). Phase (QM,QN) consumes A-half QM + B-half QN only.
// Stage plan per tile t: ph1->B1[t+1], ph2->A1[t+1], ph3->A0[t+2], ph4->B0[t+2];
// every LDS write hits a region whose last reader finished >=1 barrier earlier.
// vmcnt(4) once per tile boundary. Swizzle: src col-slot ^= row&7 (linear LDS dest).
template <int EPI>
__global__ __launch_bounds__(512)
void gemm8p(const ushort* __restrict__ A, const ushort* __restrict__ BT,
            void* __restrict__ Cout, const float* __restrict__ bias,
            int Msz, int Nsz, int Ksz, int gx) {
  extern __shared__ __align__(16) char dyn[];
  const int tid = threadIdx.x;
  const int wave = tid >> 6, lane = tid & 63;
  const int wr = wave >> 2, wc = wave & 3;
  const int fr = lane & 15, gf = lane >> 4;
  const int sl = fr & 7;

  const int nwg = gridDim.x, bid = blockIdx.x;
  const int qq = nwg >> 3;
  const int swz = (bid & 7) * qq + (bid >> 3);
  const int bx = swz % gx, by = swz / gx;
  const int brow = by * 256, bcol = bx * 256;

  const int nt = Ksz >> 6;

  // staging source (pre-swizzled): row r gets global col-slot (l&7)^(r&7)
  const int srow = lane >> 3;                    // 0..7 == row&7 of this lane's row
  const int scol = ((lane & 7) ^ srow) * 8;
  const ushort* Abase = A + (size_t)(brow + srow) * Ksz + scol;
  const ushort* Bbase = BT + (size_t)(bcol + srow) * Ksz + scol;

  auto stageA = [&](int t, int qm) {
    ushort* ldsb = (ushort*)(dyn + (t & 1) * 65536 + qm * 16384);
#pragma unroll
    for (int j = 0; j < 2; j++)
      gld_lds16(Abase + (size_t)(qm * 128 + 8 * (wave + 8 * j)) * Ksz + t * 64,
                ldsb + (wave + 8 * j) * 512);
  };
  auto stageB = [&](int t, int qn) {
    ushort* ldsb = (ushort*)(dyn + (t & 1) * 65536 + 32768 + qn * 16384);
#pragma unroll
    for (int j = 0; j < 2; j++)
      gld_lds16(Bbase + (size_t)(qn * 128 + 8 * (wave + 8 * j)) * Ksz + t * 64,
                ldsb + (wave + 8 * j) * 512);
  };

  // ds-read offsets (bytes within a 16KB half): row*128 + (slot^sl)*16
  const int ar0 = (wr * 64 + fr) * 128;
  const int ar1 = (wr * 64 + 16 + fr) * 128;
  const int ar2 = (wr * 64 + 32 + fr) * 128;
  const int ar3 = (wr * 64 + 48 + fr) * 128;
  const int br0 = (wc * 32 + fr) * 128;
  const int br1 = (wc * 32 + 16 + fr) * 128;
  const int s0 = (gf ^ sl) * 16;
  const int s1 = ((4 + gf) ^ sl) * 16;

  f32x4 acc00[4][2] = {}, acc01[4][2] = {}, acc10[4][2] = {}, acc11[4][2] = {};

  // prologue: A0_0,B0_0,B1_0,A1_0, A0_1,B0_1  (6 halves); tile0 landed at vmcnt(4)
  stageA(0, 0); stageB(0, 0); stageB(0, 1); stageA(0, 1);
  stageA(1, 0); stageB(1, 0);
  asm volatile("s_waitcnt vmcnt(4)" ::: "memory");
  __builtin_amdgcn_s_barrier();
  __builtin_amdgcn_sched_barrier(0);

#define PH8(QM, QN, ACC, STAGES, WAITS)                                              \
  {                                                                                  \
    const char* ab = dyn + cur * 65536 + (QM) * 16384;                               \
    const char* bb = dyn + cur * 65536 + 32768 + (QN) * 16384;                       \
    bf16x8 a00 = *(const bf16x8*)(ab + ar0 + s0);                                    \
    bf16x8 a10 = *(const bf16x8*)(ab + ar1 + s0);                                    \
    bf16x8 a20 = *(const bf16x8*)(ab + ar2 + s0);                                    \
    bf16x8 a30 = *(const bf16x8*)(ab + ar3 + s0);                                    \
    bf16x8 a01 = *(const bf16x8*)(ab + ar0 + s1);                                    \
    bf16x8 a11 = *(const bf16x8*)(ab + ar1 + s1);                                    \
    bf16x8 a21 = *(const bf16x8*)(ab + ar2 + s1);                                    \
    bf16x8 a31 = *(const bf16x8*)(ab + ar3 + s1);                                    \
    bf16x8 b00 = *(const bf16x8*)(bb + br0 + s0);                                    \
    bf16x8 b10 = *(const bf16x8*)(bb + br1 + s0);                                    \
    bf16x8 b01 = *(const bf16x8*)(bb + br0 + s1);                                    \
    bf16x8 b11 = *(const bf16x8*)(bb + br1 + s1);                                    \
    STAGES;                                                                          \
    WAITS;                                                                           \
    __builtin_amdgcn_s_barrier();                                                    \
    asm volatile("s_waitcnt lgkmcnt(0)" ::: "memory");                               \
    __builtin_amdgcn_sched_barrier(0);                                               \
    __builtin_amdgcn_s_setprio(1);                                                   \
    ACC[0][0] = __builtin_amdgcn_mfma_f32_16x16x32_bf16(a00, b00, ACC[0][0], 0, 0, 0); \
    ACC[0][1] = __builtin_amdgcn_mfma_f32_16x16x32_bf16(a00, b10, ACC[0][1], 0, 0, 0); \
    ACC[1][0] = __builtin_amdgcn_mfma_f32_16x16x32_bf16(a10, b00, ACC[1][0], 0, 0, 0); \
    ACC[1][1] = __builtin_amdgcn_mfma_f32_16x16x32_bf16(a10, b10, ACC[1][1], 0, 0, 0); \
    ACC[2][0] = __builtin_amdgcn_mfma_f32_16x16x32_bf16(a20, b00, ACC[2][0], 0, 0, 0); \
    ACC[2][1] = __builtin_amdgcn_mfma_f32_16x16x32_bf16(a20, b10, ACC[2][1], 0, 0, 0); \
    ACC[3][0] = __builtin_amdgcn_mfma_f32_16x16x32_bf16(a30, b00, ACC[3][0], 0, 0, 0); \
    ACC[3][1] = __builtin_amdgcn_mfma_f32_16x16x32_bf16(a30, b10, ACC[3][1], 0, 0, 0); \
    ACC[0][0] = __builtin_amdgcn_mfma_f32_16x16x32_bf16(a01, b01, ACC[0][0], 0, 0, 0); \
    ACC[0][1] = __builtin_amdgcn_mfma_f32_16x16x32_bf16(a01, b11, ACC[0][1], 0, 0, 0); \
    ACC[1][0] = __builtin_amdgcn_mfma_f32_16x16x32_bf16(a11, b01, ACC[1][0], 0, 0, 0); \
    ACC[1][1] = __builtin_amdgcn_mfma_f32_16x16x32_bf16(a11, b11, ACC[1][1], 0, 0, 0); \
    ACC[2][0] = __builtin_amdgcn_mfma_f32_16x16x32_bf16(a21, b01, ACC[2][0], 0, 0, 0); \
    ACC[2][1] = __builtin_amdgcn_mfma_f32_16x16x32_bf16(a21, b11, ACC[2][1], 0, 0, 0); \
    ACC[3][0] = __builtin_amdgcn_mfma_f32_16x16x32_bf16(a31, b01, ACC[3][0], 0, 0, 0); \
    ACC[3][1] = __builtin_amdgcn_mfma_f32_16x16x32_bf16(a31, b11, ACC[3][1], 0, 0, 0); \
    __builtin_amdgcn_s_setprio(0);                                                   \
    __builtin_amdgcn_s_barrier();                                                    \
  }

  for (int t = 0; t < nt; t++) {
    const int cur = t & 1;
    PH8(0, 0, acc00, { if (t + 1 < nt) stageB(t + 1, 1); }, {});
    PH8(0, 1, acc01, { if (t + 1 < nt) stageA(t + 1, 1); }, {});
    PH8(1, 0, acc10, { if (t + 2 < nt) stageA(t + 2, 0); }, {});
    PH8(1, 1, acc11, { if (t + 2 < nt) stageB(t + 2, 0); },
        {
          if (t + 1 < nt) {
            if (t + 2 < nt) asm volatile("s_waitcnt vmcnt(4)" ::: "memory");
            else            asm volatile("s_waitcnt vmcnt(0)" ::: "memory");
          }
        });
  }
#undef PH8

  // epilogue
  const int r4 = gf * 4;
#define WR8(ACC, QM, QN)                                                        \
  {                                                                             \
    _Pragma("unroll")                                                           \
    for (int m = 0; m < 4; m++) {                                               \
      _Pragma("unroll")                                                         \
      for (int n = 0; n < 2; n++) {                                             \
        const int col = bcol + (QN) * 128 + wc * 32 + n * 16 + fr;              \
        _Pragma("unroll")                                                       \
        for (int r = 0; r < 4; r++) {                                           \
          const int row = brow + (QM) * 128 + wr * 64 + m * 16 + r4 + r;        \
          float val = ACC[m][n][r];                                             \
          size_t o = (size_t)row * Nsz + col;                                   \
          if constexpr (EPI == 2) ((ushort*)Cout)[o] = f2bf(gelu_tanh(val + bias[col])); \
          else if constexpr (EPI == 0) ((ushort*)Cout)[o] = f2bf(val);          \
          else ((float*)Cout)[o] = val + (bias ? bias[col] : 0.f);              \
        }                                                                       \
      }                                                                         \
    }                                                                           \
  }
  WR8(acc00, 0, 0);
  WR8(acc01, 0, 1);
  WR8(acc10, 1, 0);
  WR8(acc11, 1, 1);
#undef WR8
}

// ---------------- banded attention v6: lazy-max, per-lane partial l, setprio ----------
__global__ __launch_bounds__(256)
void attn_mfma4(const ushort* __restrict__ qb, const ushort* __restrict__ kb,
                const ushort* __restrict__ Vt, const ushort* __restrict__ Rb,
                const float* __restrict__ ubias, const float* __restrict__ vbias,
                ushort* __restrict__ attb) {
  const int bid = blockIdx.x;
  const int swz = (bid & 7) * 64 + (bid >> 3);
  const int h = swz >> 5;
  const int i0 = (swz & 31) * 64;
  const int tid = threadIdx.x;
  const int wave = tid >> 6, lane = tid & 63;
  const int g = lane >> 4, fr = lane & 15;
  const int hD = h * DH_;

  __shared__ __align__(16) ushort ring[4][16][64];
  __shared__ __align__(16) ushort Pl[4][16][40];

  const int qi = i0 + wave * 16 + fr;
  bf16x8 afu[2], afv[2];
#pragma unroll
  for (int kst = 0; kst < 2; kst++) {
    const int dof = kst * 32 + g * 8;
    bf16x8 qv = *(const bf16x8*)(qb + (size_t)qi * D_ + hD + dof);
    const float* up = ubias + hD + dof;
    const float* vp = vbias + hD + dof;
    bf16x8 au, av;
#pragma unroll
    for (int j = 0; j < 8; j++) {
      float q = bf2f((ushort)qv[j]);
      au[j] = (short)f2bf(q + up[j]);
      av[j] = (short)f2bf(q + vp[j]);
    }
    afu[kst] = au; afv[kst] = av;
  }

  const int jb = 256 + i0;
  const int smax = 2303 - i0;
  const int sbase = wave * 16;

  auto produce = [&](int r0, bf16x8 rf0, bf16x8 rf1) {
    f32x4 acc = {};
    __builtin_amdgcn_s_setprio(1);
    acc = __builtin_amdgcn_mfma_f32_16x16x32_bf16(afv[0], rf0, acc, 0, 0, 0);
    acc = __builtin_amdgcn_mfma_f32_16x16x32_bf16(afv[1], rf1, acc, 0, 0, 0);
    __builtin_amdgcn_s_setprio(0);
#pragma unroll
    for (int rr = 0; rr < 4; rr++)
      ring[wave][g * 4 + rr][(r0 + fr) & 63] = f2bf(acc[rr]);
  };
  auto loadRrow = [&](int row, bf16x8* out0, bf16x8* out1) {
    const int rc = row < 0 ? 0 : row;
    *out0 = *(const bf16x8*)(Rb + (size_t)rc * D_ + hD + g * 8);
    *out1 = *(const bf16x8*)(Rb + (size_t)rc * D_ + hD + 32 + g * 8);
  };
  auto loadK = [&](int ch, bf16x8 (&kp)[2][2]) {
#pragma unroll
    for (int half = 0; half < 2; half++) {
      const int sa = sbase + ch * 32 + half * 16 + fr;
      const int jc = (jb + sa < L_ - 1) ? (jb + sa) : (L_ - 1);
      kp[half][0] = *(const bf16x8*)(kb + (size_t)jc * 1024 + hD + g * 8);
      kp[half][1] = *(const bf16x8*)(kb + (size_t)jc * 1024 + hD + 32 + g * 8);
    }
  };
  auto loadV = [&](int ch, bf16x8 (&vp)[4]) {
    int kc = jb + sbase + ch * 32 + g * 8;
    if (kc > L_ - 8) kc = L_ - 8;
#pragma unroll
    for (int n = 0; n < 4; n++)
      vp[n] = *(const bf16x8*)(Vt + (size_t)(hD + n * 16 + fr) * L_ + kc);
  };

#pragma unroll
  for (int t = 0; t < 3; t++) {
    const int r0 = 480 + t * 16;
    bf16x8 rf0, rf1;
    loadRrow(r0 + fr, &rf0, &rf1);
    produce(r0, rf0, rf1);
  }

  float m4[4], l4[4];
  f32x4 oacc[4] = {};
#pragma unroll
  for (int rr = 0; rr < 4; rr++) { m4[rr] = -1e30f; l4[rr] = 0.f; }

  bf16x8 kA[2][2], vA[4], kB[2][2], vB[4];
  bf16x8 rP0a, rP0b, rP1a, rP1b;
  loadK(0, kA); loadV(0, vA);

  auto body = [&](int ch, bf16x8 (&kU)[2][2], bf16x8 (&vU)[4],
                  bf16x8 (&kP)[2][2], bf16x8 (&vP)[4], bool first) -> bool {
    const int c0 = sbase + ch * 32;
    if (c0 > smax) return false;
    if (!first) {
      const int r0 = 480 - ch * 32;
      produce(r0, rP0a, rP0b);
      produce(r0 + 16, rP1a, rP1b);
    }
    if (ch < 16) {
      const int r0n = 480 - (ch + 1) * 32;
      loadRrow(r0n + fr, &rP0a, &rP0b);
      loadRrow(r0n + 16 + fr, &rP1a, &rP1b);
      loadK(ch + 1, kP);
      loadV(ch + 1, vP);
    }
    f32x4 sc[2];
#pragma unroll
    for (int half = 0; half < 2; half++) {
      f32x4 acc = {};
      __builtin_amdgcn_s_setprio(1);
      acc = __builtin_amdgcn_mfma_f32_16x16x32_bf16(afu[0], kU[half][0], acc, 0, 0, 0);
      acc = __builtin_amdgcn_mfma_f32_16x16x32_bf16(afu[1], kU[half][1], acc, 0, 0, 0);
      __builtin_amdgcn_s_setprio(0);
      const int rb2 = 512 + g * 4 - (ch * 32 + half * 16 + fr);
      const int sa = c0 + half * 16 + fr;
#pragma unroll
      for (int rr = 0; rr < 4; rr++) {
        const int r = rb2 + rr;
        const float bd = bf2f(ring[wave][g * 4 + rr][r & 63]);
        const bool valid = ((unsigned)r <= 512u) && (sa <= smax);
        sc[half][rr] = valid ? (acc[rr] + bd) * 0.125f : -1e30f;
      }
    }
    if (first) {
      f32x4 cm;
#pragma unroll
      for (int rr = 0; rr < 4; rr++) cm[rr] = fmaxf(sc[0][rr], sc[1][rr]);
#pragma unroll
      for (int off = 8; off; off >>= 1)
#pragma unroll
        for (int rr = 0; rr < 4; rr++) cm[rr] = fmaxf(cm[rr], __shfl_xor(cm[rr], off));
#pragma unroll
      for (int rr = 0; rr < 4; rr++) m4[rr] = cm[rr];
    } else {
      bool rise = false;
#pragma unroll
      for (int rr = 0; rr < 4; rr++)
        rise |= (fmaxf(sc[0][rr], sc[1][rr]) > m4[rr] + 8.f);
      if (__any(rise)) {
        f32x4 cm;
#pragma unroll
        for (int rr = 0; rr < 4; rr++) cm[rr] = fmaxf(sc[0][rr], sc[1][rr]);
#pragma unroll
        for (int off = 8; off; off >>= 1)
#pragma unroll
          for (int rr = 0; rr < 4; rr++) cm[rr] = fmaxf(cm[rr], __shfl_xor(cm[rr], off));
#pragma unroll
        for (int rr = 0; rr < 4; rr++) {
          const float nm = fmaxf(m4[rr], cm[rr]);
          const float esc = __expf(m4[rr] - nm);
          m4[rr] = nm;
          l4[rr] *= esc;
#pragma unroll
          for (int n = 0; n < 4; n++) oacc[n][rr] *= esc;
        }
      }
    }
    f32x4 pA, pB;
#pragma unroll
    for (int rr = 0; rr < 4; rr++) {
      pA[rr] = __expf(sc[0][rr] - m4[rr]);
      pB[rr] = __expf(sc[1][rr] - m4[rr]);
      l4[rr] += pA[rr] + pB[rr];
    }
#pragma unroll
    for (int rr = 0; rr < 4; rr++) {
      Pl[wave][g * 4 + rr][fr]      = f2bf(pA[rr]);
      Pl[wave][g * 4 + rr][16 + fr] = f2bf(pB[rr]);
    }
    bf16x8 pf = *(const bf16x8*)&Pl[wave][fr][g * 8];
    __builtin_amdgcn_s_setprio(1);
#pragma unroll
    for (int n = 0; n < 4; n++)
      oacc[n] = __builtin_amdgcn_mfma_f32_16x16x32_bf16(pf, vU[n], oacc[n], 0, 0, 0);
    __builtin_amdgcn_s_setprio(0);
    return true;
  };

  bool cont = body(0, kA, vA, kB, vB, true);
  for (int ch = 1; ch < 17 && cont; ch += 2) {
    cont = body(ch, kB, vB, kA, vA, false);
    if (!cont || ch + 1 >= 17) break;
    cont = body(ch + 1, kA, vA, kB, vB, false);
  }

#pragma unroll
  for (int off = 8; off; off >>= 1)
#pragma unroll
    for (int rr = 0; rr < 4; rr++) l4[rr] += __shfl_xor(l4[rr], off);
#pragma unroll
  for (int rr = 0; rr < 4; rr++) {
    const float inv = 1.f / l4[rr];
    const size_t rowo = (size_t)(i0 + sbase + g * 4 + rr) * D_ + hD;
#pragma unroll
    for (int n = 0; n < 4; n++)
      attb[rowo + n * 16 + fr] = f2bf(oacc[n][rr] * inv);
  }
}

// ---------------- residual + LayerNorm (2 or 3 addends) ----------------
__global__ __launch_bounds__(256)
void ln_kernel(const float* __restrict__ a, const float* __restrict__ b,
               const float* __restrict__ c,
               const float* __restrict__ gamma, const float* __restrict__ beta,
               float* __restrict__ outf, ushort* __restrict__ outb) {
  const int row = blockIdx.x;
  const int tid = threadIdx.x;
  const int wave = tid >> 6, lane = tid & 63;
  float4 va = ((const float4*)(a + (size_t)row * D_))[tid];
  float4 vb4 = ((const float4*)(b + (size_t)row * D_))[tid];
  float4 xv;
  xv.x = va.x + vb4.x; xv.y = va.y + vb4.y; xv.z = va.z + vb4.z; xv.w = va.w + vb4.w;
  if (c) {
    float4 vc = ((const float4*)(c + (size_t)row * D_))[tid];
    xv.x += vc.x; xv.y += vc.y; xv.z += vc.z; xv.w += vc.w;
  }
  float s = xv.x + xv.y + xv.z + xv.w;
  float q = xv.x * xv.x + xv.y * xv.y + xv.z * xv.z + xv.w * xv.w;
#pragma unroll
  for (int off = 32; off; off >>= 1) { s += __shfl_xor(s, off); q += __shfl_xor(q, off); }
  __shared__ float red[8];
  if (lane == 0) { red[wave * 2] = s; red[wave * 2 + 1] = q; }
  __syncthreads();
  float ts = red[0] + red[2] + red[4] + red[6];
  float tq = red[1] + red[3] + red[5] + red[7];
  float mu = ts * (1.f / D_);
  float var = tq * (1.f / D_) - mu * mu;
  float rs = rsqrtf(var + 1e-5f);
  float4 g4 = ((const float4*)gamma)[tid];
  float4 be4 = ((const float4*)beta)[tid];
  float4 y;
  y.x = (xv.x - mu) * rs * g4.x + be4.x;
  y.y = (xv.y - mu) * rs * g4.y + be4.y;
  y.z = (xv.z - mu) * rs * g4.z + be4.z;
  y.w = (xv.w - mu) * rs * g4.w + be4.w;
  ((float4*)(outf + (size_t)row * D_))[tid] = y;
  if (outb) ((ushort4*)(outb + (size_t)row * D_))[tid] = pack4(y);
}

extern "C" void kernel_launch(void* const* d_in, const int* in_sizes, int n_in,
                              void* d_out, int out_size, void* d_ws, size_t ws_size,
                              hipStream_t stream) {
  const float* x    = (const float*)d_in[0];
  const float* mem  = (const float*)d_in[1];
  const float* Wq   = (const float*)d_in[2];
  const float* Wk   = (const float*)d_in[3];
  const float* Wv   = (const float*)d_in[4];
  const float* Wo   = (const float*)d_in[5];
  const float* Wr   = (const float*)d_in[6];
  const float* u    = (const float*)d_in[7];
  const float* v    = (const float*)d_in[8];
  const float* ln1g = (const float*)d_in[9];
  const float* ln1b = (const float*)d_in[10];
  const float* W1   = (const float*)d_in[11];
  const float* b1   = (const float*)d_in[12];
  const float* W2   = (const float*)d_in[13];
  const float* b2   = (const float*)d_in[14];
  const float* ln2g = (const float*)d_in[15];
  const float* ln2b = (const float*)d_in[16];
  float* out = (float*)d_out;

  char* ws = (char*)d_ws;
  size_t off = 0;
  auto take = [&](size_t n) { char* p = ws + off; off += (n + 255) & ~(size_t)255; return p; };

  ushort* WqT = (ushort*)take(2097152);
  ushort* WkT = (ushort*)take(2097152);   // WkT||WvT contiguous = [2048][1024]
  ushort* WvT = (ushort*)take(2097152);
  ushort* WoT = (ushort*)take(2097152);
  ushort* WrT = (ushort*)take(2097152);
  ushort* W1T = (ushort*)take(8388608);   // [4096][1024]
  ushort* W2T = (ushort*)take(8388608);   // [1024][4096]

  char* regA = take(8388608);             // kvb + remb; later reused for fbuf
  ushort* kvb  = (ushort*)regA;
  ushort* remb = (ushort*)(regA + 5242880);
  float*  fbuf = (float*)regA;            // FFN2 z0 (+bias)

  char* regB = take(20185088);            // qb,kb,Vt,Rb,attb; overlays: o2b, g
  ushort* qb   = (ushort*)regB;
  ushort* kb   = (ushort*)(regB + 4194304);
  ushort* Vt   = (ushort*)(regB + 9437184);           // [1024][2560]
  ushort* Rb   = (ushort*)(regB + 14680064);
  ushort* attb = (ushort*)(regB + 15990784);
  float*  o2b  = (float*)regB;                        // Wo z=1 partial
  ushort* g    = (ushort*)regB;                       // FFN1 out (16MB)

  float*  o2 = (float*)take(8388608);     // Wo z=0 partial; later FFN2 z1 partial
  float*  h  = (float*)take(8388608);
  ushort* hb = (ushort*)take(4194304);

  prep_kernel<<<17152, 256, 0, stream>>>(x, mem, Wq, Wk, Wv, Wo, Wr, W1, W2,
                                         WqT, WkT, WvT, WoT, WrT, W1T, W2T, kvb, remb);

  proj_gemm<<<976, 256, 0, stream>>>(kvb, WqT, WkT, WrT, remb, qb, kb, Vt, Rb);

  attn_mfma4<<<512, 256, 0, stream>>>(qb, kb, Vt, Rb, u, v, attb);

  gemm_kern<64, 128, 1, 2><<<512, 256, 0, stream>>>(attb, WoT, o2, o2b, nullptr,
                                                    2048, 1024, 512, 1024, 8);
  ln_kernel<<<2048, 256, 0, stream>>>(x, o2, o2b, ln1g, ln1b, h, hb);

  // FFN1: 8-phase 256x256 kernel, 128 blocks, 128KB dynamic LDS
  gemm8p<2><<<128, 512, 131072, stream>>>(hb, W1T, g, b1, 2048, 4096, 1024, 16);

  gemm_kern<64, 128, 3, 2><<<512, 256, 0, stream>>>(g, W2T, fbuf, o2, b2,
                                                    2048, 1024, 2048, 4096, 8);
  ln_kernel<<<2048, 256, 0, stream>>>(h, fbuf, o2, ln2g, ln2b, out, nullptr);
}

// Round 12
// 208.886 us; speedup vs baseline: 1.4268x; 1.2094x over previous
//
#include <hip/hip_runtime.h>
#include <hip/hip_bf16.h>
#include <cstdint>

#define S_ 2048
#define M_ 512
#define L_ 2560
#define D_ 1024
#define F_ 4096
#define H_ 16
#define DH_ 64
#define W_ 256
#define NR_ 513
#define NRP_ 640

typedef unsigned int uint32;
typedef __attribute__((ext_vector_type(8))) short bf16x8;
typedef __attribute__((ext_vector_type(4))) float f32x4;

__device__ __forceinline__ ushort f2bf(float f) {
  uint32 u = __builtin_bit_cast(uint32, f);
  u += 0x7FFFu + ((u >> 16) & 1u);
  return (ushort)(u >> 16);
}
__device__ __forceinline__ float bf2f(ushort s) {
  uint32 u = ((uint32)s) << 16;
  return __builtin_bit_cast(float, u);
}
__device__ __forceinline__ ushort4 pack4(float4 vf) {
  ushort4 r;
  r.x = f2bf(vf.x); r.y = f2bf(vf.y); r.z = f2bf(vf.z); r.w = f2bf(vf.w);
  return r;
}
__device__ __forceinline__ float gelu_tanh(float x) {
  float t = 0.7978845608028654f * x * (1.f + 0.044715f * x * x);
  float e = __expf(2.f * t);
  float th = 1.f - 2.f / (e + 1.f);
  return 0.5f * x * (1.f + th);
}

// async global(16B/lane) -> LDS, wave-uniform LDS base + lane*16
__device__ __forceinline__ void gld_lds16(const ushort* g, ushort* l) {
  __builtin_amdgcn_global_load_lds((const __attribute__((address_space(1))) void*)g,
                                   (__attribute__((address_space(3))) void*)l, 16, 0, 0);
}

// ================= fused prep: 7 weight transposes + kv pack + sinusoid =================
__device__ __forceinline__ void tr_tile(const float* __restrict__ in, ushort* __restrict__ out,
                                        int R, int C, int c0, int r0, int tx, int ty,
                                        float (*tile)[33]) {
#pragma unroll
  for (int i = 0; i < 4; i++)
    tile[ty + i * 8][tx] = in[(size_t)(r0 + ty + i * 8) * C + c0 + tx];
  __syncthreads();
#pragma unroll
  for (int i = 0; i < 4; i++)
    out[(size_t)(c0 + ty + i * 8) * R + r0 + tx] = f2bf(tile[tx][ty + i * 8]);
}

__global__ __launch_bounds__(256)
void prep_kernel(const float* __restrict__ x, const float* __restrict__ mem,
                 const float* __restrict__ Wq, const float* __restrict__ Wk,
                 const float* __restrict__ Wv, const float* __restrict__ Wo,
                 const float* __restrict__ Wr, const float* __restrict__ W1,
                 const float* __restrict__ W2,
                 ushort* __restrict__ WqT, ushort* __restrict__ WkT,
                 ushort* __restrict__ WvT, ushort* __restrict__ WoT,
                 ushort* __restrict__ WrT, ushort* __restrict__ W1T,
                 ushort* __restrict__ W2T,
                 ushort* __restrict__ kvb, ushort* __restrict__ remb) {
  __shared__ float tile[32][33];
  const int bid = blockIdx.x;
  const int tid = threadIdx.x;
  const int tx = tid & 31, ty = tid >> 5;

  if (bid < 5120) {
    const int which = bid >> 10, idx = bid & 1023;
    const float* ins[5] = {Wq, Wk, Wv, Wo, Wr};
    ushort* outs[5] = {WqT, WkT, WvT, WoT, WrT};
    tr_tile(ins[which], outs[which], 1024, 1024, (idx & 31) * 32, (idx >> 5) * 32, tx, ty, tile);
  } else if (bid < 9216) {
    const int idx = bid - 5120;
    tr_tile(W1, W1T, 1024, 4096, (idx % 128) * 32, (idx / 128) * 32, tx, ty, tile);
  } else if (bid < 13312) {
    const int idx = bid - 9216;
    tr_tile(W2, W2T, 4096, 1024, (idx & 31) * 32, (idx >> 5) * 32, tx, ty, tile);
  } else if (bid < 15872) {
    const int k = (bid - 13312) * 256 + tid;
    const int l = k >> 8, c = k & 255;
    const float4* src = (l < M_) ? (const float4*)(mem + (size_t)l * D_)
                                 : (const float4*)(x + (size_t)(l - M_) * D_);
    ((ushort4*)kvb)[k] = pack4(src[c]);
  } else {
    const int idx = (bid - 15872) * 256 + tid;
    const int r = idx >> 9, f = idx & 511;
    if (r < NR_) {
      float invf = expf(-(float)f * (9.210340371976184f / 512.0f));
      float ang = (float)(r - W_) * invf;
      remb[(size_t)r * D_ + f] = f2bf(sinf(ang));
      remb[(size_t)r * D_ + 512 + f] = f2bf(cosf(ang));
    } else if (r < NRP_) {
      remb[(size_t)r * D_ + f] = 0;
      remb[(size_t)r * D_ + 512 + f] = 0;
    }
  }
}

// ====== 2-phase MFMA GEMM core (r8 config): BK=64, BM x 128 tiles ======
template <int BM, int BN, int EPI, int SPLITK>
__device__ __forceinline__
void gemm_core(const ushort* __restrict__ A, const ushort* __restrict__ BT,
               void* __restrict__ Cout, void* __restrict__ Cout2,
               const float* __restrict__ bias, int Msz, int Nsz, int Ksz, int Kstride,
               int gx, int bid, int nwg, ushort* smem) {
  constexpr int PA = BM * 8 + 16;
  constexpr int PB = BN * 8 + 16;
  constexpr int MFR = BM / 32;
  constexpr int NFR = BN / 32;
  constexpr int NAI = (BM / 64) * 8;
  constexpr int NBI = (BN / 64) * 8;
  constexpr int NPW = (NAI + NBI) / 4;
  const int tid = threadIdx.x;
  const int wave = tid >> 6, lane = tid & 63;
  const int wr = wave >> 1, wc = wave & 1;

  const int q = nwg >> 3;
  const int swz = (bid & 7) * q + (bid >> 3);
  const int gy = Msz / BM;
  const int bx = swz % gx;
  const int rest = swz / gx;
  const int by = rest % gy;
  const int bz = rest / gy;

  const int brow = by * BM, bcol = bx * BN;
  const int koff = (SPLITK > 1) ? bz * Ksz : 0;

  ushort* As = smem;
  ushort* Bs = smem + 2 * 8 * PA;

  const ushort* gsrc[NPW]; int ldst[NPW];
#pragma unroll
  for (int i = 0; i < NPW; i++) {
    const int idx = i * 4 + wave;
    if (i < NAI / 4) {
      const int rowbase = (idx >> 3) * 64, kg = idx & 7;
      gsrc[i] = A + (size_t)(brow + rowbase + lane) * Kstride + koff + kg * 8;
      ldst[i] = kg * PA + rowbase * 8;
    } else {
      const int b = idx - NAI;
      const int rowbase = (b >> 3) * 64, kg = b & 7;
      gsrc[i] = BT + (size_t)(bcol + rowbase + lane) * Kstride + koff + kg * 8;
      ldst[i] = kg * PB + rowbase * 8;
    }
  }

  f32x4 acc[MFR][NFR] = {};
  const int kgf = lane >> 4, fr = lane & 15;
  const int nk = Ksz >> 6;

  auto stage = [&](int t, int buf) {
    const int ko = t * 64;
    ushort* ab = As + buf * 8 * PA;
    ushort* bb = Bs + buf * 8 * PB;
#pragma unroll
    for (int i = 0; i < NPW; i++) {
      ushort* base = (i < NAI / 4) ? ab : bb;
      gld_lds16(gsrc[i] + ko, base + ldst[i]);
    }
  };

  stage(0, 0);
  asm volatile("s_waitcnt vmcnt(0)" ::: "memory");
  __builtin_amdgcn_s_barrier();
  __builtin_amdgcn_sched_barrier(0);

  int cur = 0;
  for (int t = 0; t < nk; t++) {
    if (t + 1 < nk) stage(t + 1, cur ^ 1);
    ushort* ab = As + cur * 8 * PA;
    ushort* bb = Bs + cur * 8 * PB;
#pragma unroll
    for (int kk = 0; kk < 2; kk++) {
      bf16x8 af[MFR], bfv[NFR];
#pragma unroll
      for (int m = 0; m < MFR; m++)
        af[m] = *(const bf16x8*)(ab + (kk * 4 + kgf) * PA + (wr * (BM / 2) + m * 16 + fr) * 8);
#pragma unroll
      for (int n = 0; n < NFR; n++)
        bfv[n] = *(const bf16x8*)(bb + (kk * 4 + kgf) * PB + (wc * (BN / 2) + n * 16 + fr) * 8);
#pragma unroll
      for (int m = 0; m < MFR; m++)
#pragma unroll
        for (int n = 0; n < NFR; n++)
          acc[m][n] = __builtin_amdgcn_mfma_f32_16x16x32_bf16(af[m], bfv[n], acc[m][n], 0, 0, 0);
    }
    if (t + 1 < nk) {
      asm volatile("s_waitcnt vmcnt(0)" ::: "memory");
      __builtin_amdgcn_s_barrier();
      __builtin_amdgcn_sched_barrier(0);
    }
    cur ^= 1;
  }

  const int r4 = (lane >> 4) * 4;
  float* co = (float*)Cout;
  bool addb = (EPI == 3);
  if constexpr (SPLITK == 2) {
    if (bz == 1) { co = (float*)Cout2; addb = false; }
  }
#pragma unroll
  for (int m = 0; m < MFR; m++) {
#pragma unroll
    for (int n = 0; n < NFR; n++) {
      const int col = bcol + wc * (BN / 2) + n * 16 + fr;
#pragma unroll
      for (int r = 0; r < 4; r++) {
        const int row = brow + wr * (BM / 2) + m * 16 + r4 + r;
        float val = acc[m][n][r];
        size_t o = (size_t)row * Nsz + col;
        if constexpr (EPI == 0) ((ushort*)Cout)[o] = f2bf(val);
        else if constexpr (EPI == 2) ((ushort*)Cout)[o] = f2bf(gelu_tanh(val + bias[col]));
        else co[o] = addb ? val + bias[col] : val;
      }
    }
  }
}

template <int BM, int BN, int EPI, int SPLITK>
__global__ __launch_bounds__(256)
void gemm_kern(const ushort* __restrict__ A, const ushort* __restrict__ BT,
               void* __restrict__ Cout, void* __restrict__ Cout2,
               const float* __restrict__ bias, int Msz, int Nsz, int Ksz, int Kstride,
               int gx) {
  constexpr int PA = BM * 8 + 16, PB = BN * 8 + 16;
  __shared__ __align__(16) ushort smem[2 * 8 * (PA + PB)];
  gemm_core<BM, BN, EPI, SPLITK>(A, BT, Cout, Cout2, bias, Msz, Nsz, Ksz, Kstride,
                                 gx, blockIdx.x, gridDim.x, smem);
}

// ====== 8-phase 128x256 GEMM core (T2+T3+T4+T5), full-chip grids ======
// 8 waves (512 thr). LDS/buf: [A0 8K][A1 8K][B0 16K][B1 16K] = 48KB, 2 bufs = 96KB.
// Phase (QM,QN): A-half QM (64 rows) x B-half QN (128 cols); 8 MFMA + 8 ds_read_b128.
// Stage plan/tile: ph1->B1[t+1], ph2->A1[t+1], ph3->A0[t+2], ph4->B0[t+2].
// Steady-state wait: vmcnt(3) once per tile (9 in flight, drain 6 oldest).
// EPI: 0 bf16; 2 bf16 gelu(c+bias); 5 split kb/Vt.
template <int EPI>
__device__ __forceinline__
void gemm8p2_core(const ushort* __restrict__ A, const ushort* __restrict__ BT,
                  void* __restrict__ Cout, void* __restrict__ Cout2,
                  const float* __restrict__ bias, int Msz, int Nsz, int Ksz, int Kstride,
                  int gx, int bid, int nwg, char* dyn) {
  const int tid = threadIdx.x;
  const int wave = tid >> 6, lane = tid & 63;
  const int wr = wave >> 2, wc = wave & 3;
  const int fr = lane & 15, gf = lane >> 4;
  const int sl = fr & 7;

  // m204 general bijective XCD swizzle (works for any nwg)
  const int xcd = bid & 7, idx = bid >> 3;
  const int q = nwg >> 3, r8 = nwg & 7;
  const int swz = (xcd < r8 ? xcd * (q + 1) : r8 * (q + 1) + (xcd - r8) * q) + idx;
  const int bx = swz % gx, by = swz / gx;
  const int brow = by * 128, bcol = bx * 256;

  const int nt = Ksz >> 6;

  // staging: thread tid loads row tid>>3, pre-swizzled col-slot (tid&7)^(row&7)
  const int srow = tid >> 3;
  const int scol = ((tid & 7) ^ (srow & 7)) * 8;
  const ushort* Ab = A + (size_t)(brow + srow) * Kstride + scol;
  const ushort* Bb = BT + (size_t)(bcol + srow) * Kstride + scol;

  auto stageA = [&](int t, int qm) {
    gld_lds16(Ab + (size_t)(qm * 64) * Kstride + t * 64,
              (ushort*)(dyn + (t & 1) * 49152 + qm * 8192) + wave * 512);
  };
  auto stageB = [&](int t, int qn) {
#pragma unroll
    for (int j = 0; j < 2; j++)
      gld_lds16(Bb + (size_t)(qn * 128 + j * 64) * Kstride + t * 64,
                (ushort*)(dyn + (t & 1) * 49152 + 16384 + qn * 16384 + j * 8192) + wave * 512);
  };

  // read offsets (bytes): row*128 + ((sigma ^ sl) * 16)
  const int ar0 = (wr * 32 + fr) * 128;
  const int ar1 = (wr * 32 + 16 + fr) * 128;
  const int br0 = (wc * 32 + fr) * 128;
  const int br1 = (wc * 32 + 16 + fr) * 128;
  const int s0 = (gf ^ sl) * 16;
  const int s1 = ((4 + gf) ^ sl) * 16;

  f32x4 acc00[2][2] = {}, acc01[2][2] = {}, acc10[2][2] = {}, acc11[2][2] = {};

  // prologue: tile0 (A0,B0,B1,A1 = 6 instr) + tile1 A0,B0 (3 instr); drain tile0
  stageA(0, 0); stageB(0, 0); stageB(0, 1); stageA(0, 1);
  stageA(1, 0); stageB(1, 0);
  asm volatile("s_waitcnt vmcnt(3)" ::: "memory");
  __builtin_amdgcn_s_barrier();
  __builtin_amdgcn_sched_barrier(0);

#define PH4(QM, QN, ACC, STAGES, WAITS)                                                 \
  {                                                                                     \
    const char* ab = dyn + cur * 49152 + (QM) * 8192;                                   \
    const char* bb = dyn + cur * 49152 + 16384 + (QN) * 16384;                          \
    bf16x8 a00 = *(const bf16x8*)(ab + ar0 + s0);                                       \
    bf16x8 a10 = *(const bf16x8*)(ab + ar1 + s0);                                       \
    bf16x8 a01 = *(const bf16x8*)(ab + ar0 + s1);                                       \
    bf16x8 a11 = *(const bf16x8*)(ab + ar1 + s1);                                       \
    bf16x8 b00 = *(const bf16x8*)(bb + br0 + s0);                                       \
    bf16x8 b10 = *(const bf16x8*)(bb + br1 + s0);                                       \
    bf16x8 b01 = *(const bf16x8*)(bb + br0 + s1);                                       \
    bf16x8 b11 = *(const bf16x8*)(bb + br1 + s1);                                       \
    STAGES;                                                                             \
    WAITS;                                                                              \
    __builtin_amdgcn_s_barrier();                                                       \
    asm volatile("s_waitcnt lgkmcnt(0)" ::: "memory");                                  \
    __builtin_amdgcn_sched_barrier(0);                                                  \
    __builtin_amdgcn_s_setprio(1);                                                      \
    ACC[0][0] = __builtin_amdgcn_mfma_f32_16x16x32_bf16(a00, b00, ACC[0][0], 0, 0, 0);  \
    ACC[0][1] = __builtin_amdgcn_mfma_f32_16x16x32_bf16(a00, b10, ACC[0][1], 0, 0, 0);  \
    ACC[1][0] = __builtin_amdgcn_mfma_f32_16x16x32_bf16(a10, b00, ACC[1][0], 0, 0, 0);  \
    ACC[1][1] = __builtin_amdgcn_mfma_f32_16x16x32_bf16(a10, b10, ACC[1][1], 0, 0, 0);  \
    ACC[0][0] = __builtin_amdgcn_mfma_f32_16x16x32_bf16(a01, b01, ACC[0][0], 0, 0, 0);  \
    ACC[0][1] = __builtin_amdgcn_mfma_f32_16x16x32_bf16(a01, b11, ACC[0][1], 0, 0, 0);  \
    ACC[1][0] = __builtin_amdgcn_mfma_f32_16x16x32_bf16(a11, b01, ACC[1][0], 0, 0, 0);  \
    ACC[1][1] = __builtin_amdgcn_mfma_f32_16x16x32_bf16(a11, b11, ACC[1][1], 0, 0, 0);  \
    __builtin_amdgcn_s_setprio(0);                                                      \
    __builtin_amdgcn_s_barrier();                                                       \
  }

  for (int t = 0; t < nt; t++) {
    const int cur = t & 1;
    PH4(0, 0, acc00, { if (t + 1 < nt) stageB(t + 1, 1); }, {});
    PH4(0, 1, acc01, { if (t + 1 < nt) stageA(t + 1, 1); }, {});
    PH4(1, 0, acc10, { if (t + 2 < nt) stageA(t + 2, 0); }, {});
    PH4(1, 1, acc11, { if (t + 2 < nt) stageB(t + 2, 0); },
        {
          if (t + 1 < nt) {
            if (t + 2 < nt) asm volatile("s_waitcnt vmcnt(3)" ::: "memory");
            else            asm volatile("s_waitcnt vmcnt(0)" ::: "memory");
          }
        });
  }
#undef PH4

  // epilogue
  const int r4 = gf * 4;
  auto wrq = [&](const f32x4 (&ACC)[2][2], int QM, int QN) {
#pragma unroll
    for (int m = 0; m < 2; m++) {
#pragma unroll
      for (int n = 0; n < 2; n++) {
        const int col = bcol + QN * 128 + wc * 32 + n * 16 + fr;
        const int row0 = brow + QM * 64 + wr * 32 + m * 16 + r4;
        if constexpr (EPI == 5) {
          if (col < 1024) {
#pragma unroll
            for (int r = 0; r < 4; r++)
              ((ushort*)Cout)[(size_t)(row0 + r) * 1024 + col] = f2bf(ACC[m][n][r]);
          } else {
            ushort4 pk;
            pk.x = f2bf(ACC[m][n][0]); pk.y = f2bf(ACC[m][n][1]);
            pk.z = f2bf(ACC[m][n][2]); pk.w = f2bf(ACC[m][n][3]);
            *(ushort4*)((ushort*)Cout2 + (size_t)(col - 1024) * Msz + row0) = pk;
          }
        } else {
#pragma unroll
          for (int r = 0; r < 4; r++) {
            float val = ACC[m][n][r];
            size_t o = (size_t)(row0 + r) * Nsz + col;
            if constexpr (EPI == 2) ((ushort*)Cout)[o] = f2bf(gelu_tanh(val + bias[col]));
            else ((ushort*)Cout)[o] = f2bf(val);
          }
        }
      }
    }
  };
  wrq(acc00, 0, 0);
  wrq(acc01, 0, 1);
  wrq(acc10, 1, 0);
  wrq(acc11, 1, 1);
}

template <int EPI>
__global__ __launch_bounds__(512)
void gemm8p2_kern(const ushort* __restrict__ A, const ushort* __restrict__ BT,
                  void* __restrict__ Cout, void* __restrict__ Cout2,
                  const float* __restrict__ bias, int Msz, int Nsz, int Ksz, int Kstride,
                  int gx) {
  extern __shared__ __align__(16) char dyn[];
  gemm8p2_core<EPI>(A, BT, Cout, Cout2, bias, Msz, Nsz, Ksz, Kstride,
                    gx, blockIdx.x, gridDim.x, dyn);
}

// merged Q / KV / R projection on the 8-phase core: 64 + 160 + 20 = 244 blocks
__global__ __launch_bounds__(512)
void proj8p(const ushort* __restrict__ kvb, const ushort* __restrict__ WqT,
            const ushort* __restrict__ WkvT, const ushort* __restrict__ WrT,
            const ushort* __restrict__ remb,
            ushort* __restrict__ qb, ushort* __restrict__ kb,
            ushort* __restrict__ Vt, ushort* __restrict__ Rb) {
  extern __shared__ __align__(16) char dyn[];
  const int bid = blockIdx.x;
  if (bid < 64) {
    gemm8p2_core<0>(kvb + 512 * 1024, WqT, qb, nullptr, nullptr,
                    2048, 1024, 1024, 1024, 4, bid, 64, dyn);
  } else if (bid < 224) {
    gemm8p2_core<5>(kvb, WkvT, kb, Vt, nullptr,
                    2560, 2048, 1024, 1024, 8, bid - 64, 160, dyn);
  } else {
    gemm8p2_core<0>(remb, WrT, Rb, nullptr, nullptr,
                    640, 1024, 1024, 1024, 4, bid - 224, 20, dyn);
  }
}

// ---------------- banded attention v6: lazy-max, per-lane partial l, setprio ----------
__global__ __launch_bounds__(256)
void attn_mfma4(const ushort* __restrict__ qb, const ushort* __restrict__ kb,
                const ushort* __restrict__ Vt, const ushort* __restrict__ Rb,
                const float* __restrict__ ubias, const float* __restrict__ vbias,
                ushort* __restrict__ attb) {
  const int bid = blockIdx.x;
  const int swz = (bid & 7) * 64 + (bid >> 3);
  const int h = swz >> 5;
  const int i0 = (swz & 31) * 64;
  const int tid = threadIdx.x;
  const int wave = tid >> 6, lane = tid & 63;
  const int g = lane >> 4, fr = lane & 15;
  const int hD = h * DH_;

  __shared__ __align__(16) ushort ring[4][16][64];
  __shared__ __align__(16) ushort Pl[4][16][40];

  const int qi = i0 + wave * 16 + fr;
  bf16x8 afu[2], afv[2];
#pragma unroll
  for (int kst = 0; kst < 2; kst++) {
    const int dof = kst * 32 + g * 8;
    bf16x8 qv = *(const bf16x8*)(qb + (size_t)qi * D_ + hD + dof);
    const float* up = ubias + hD + dof;
    const float* vp = vbias + hD + dof;
    bf16x8 au, av;
#pragma unroll
    for (int j = 0; j < 8; j++) {
      float q = bf2f((ushort)qv[j]);
      au[j] = (short)f2bf(q + up[j]);
      av[j] = (short)f2bf(q + vp[j]);
    }
    afu[kst] = au; afv[kst] = av;
  }

  const int jb = 256 + i0;
  const int smax = 2303 - i0;
  const int sbase = wave * 16;

  auto produce = [&](int r0, bf16x8 rf0, bf16x8 rf1) {
    f32x4 acc = {};
    __builtin_amdgcn_s_setprio(1);
    acc = __builtin_amdgcn_mfma_f32_16x16x32_bf16(afv[0], rf0, acc, 0, 0, 0);
    acc = __builtin_amdgcn_mfma_f32_16x16x32_bf16(afv[1], rf1, acc, 0, 0, 0);
    __builtin_amdgcn_s_setprio(0);
#pragma unroll
    for (int rr = 0; rr < 4; rr++)
      ring[wave][g * 4 + rr][(r0 + fr) & 63] = f2bf(acc[rr]);
  };
  auto loadRrow = [&](int row, bf16x8* out0, bf16x8* out1) {
    const int rc = row < 0 ? 0 : row;
    *out0 = *(const bf16x8*)(Rb + (size_t)rc * D_ + hD + g * 8);
    *out1 = *(const bf16x8*)(Rb + (size_t)rc * D_ + hD + 32 + g * 8);
  };
  auto loadK = [&](int ch, bf16x8 (&kp)[2][2]) {
#pragma unroll
    for (int half = 0; half < 2; half++) {
      const int sa = sbase + ch * 32 + half * 16 + fr;
      const int jc = (jb + sa < L_ - 1) ? (jb + sa) : (L_ - 1);
      kp[half][0] = *(const bf16x8*)(kb + (size_t)jc * 1024 + hD + g * 8);
      kp[half][1] = *(const bf16x8*)(kb + (size_t)jc * 1024 + hD + 32 + g * 8);
    }
  };
  auto loadV = [&](int ch, bf16x8 (&vp)[4]) {
    int kc = jb + sbase + ch * 32 + g * 8;
    if (kc > L_ - 8) kc = L_ - 8;
#pragma unroll
    for (int n = 0; n < 4; n++)
      vp[n] = *(const bf16x8*)(Vt + (size_t)(hD + n * 16 + fr) * L_ + kc);
  };

#pragma unroll
  for (int t = 0; t < 3; t++) {
    const int r0 = 480 + t * 16;
    bf16x8 rf0, rf1;
    loadRrow(r0 + fr, &rf0, &rf1);
    produce(r0, rf0, rf1);
  }

  float m4[4], l4[4];
  f32x4 oacc[4] = {};
#pragma unroll
  for (int rr = 0; rr < 4; rr++) { m4[rr] = -1e30f; l4[rr] = 0.f; }

  bf16x8 kA[2][2], vA[4], kB[2][2], vB[4];
  bf16x8 rP0a, rP0b, rP1a, rP1b;
  loadK(0, kA); loadV(0, vA);

  auto body = [&](int ch, bf16x8 (&kU)[2][2], bf16x8 (&vU)[4],
                  bf16x8 (&kP)[2][2], bf16x8 (&vP)[4], bool first) -> bool {
    const int c0 = sbase + ch * 32;
    if (c0 > smax) return false;
    if (!first) {
      const int r0 = 480 - ch * 32;
      produce(r0, rP0a, rP0b);
      produce(r0 + 16, rP1a, rP1b);
    }
    if (ch < 16) {
      const int r0n = 480 - (ch + 1) * 32;
      loadRrow(r0n + fr, &rP0a, &rP0b);
      loadRrow(r0n + 16 + fr, &rP1a, &rP1b);
      loadK(ch + 1, kP);
      loadV(ch + 1, vP);
    }
    f32x4 sc[2];
#pragma unroll
    for (int half = 0; half < 2; half++) {
      f32x4 acc = {};
      __builtin_amdgcn_s_setprio(1);
      acc = __builtin_amdgcn_mfma_f32_16x16x32_bf16(afu[0], kU[half][0], acc, 0, 0, 0);
      acc = __builtin_amdgcn_mfma_f32_16x16x32_bf16(afu[1], kU[half][1], acc, 0, 0, 0);
      __builtin_amdgcn_s_setprio(0);
      const int rb2 = 512 + g * 4 - (ch * 32 + half * 16 + fr);
      const int sa = c0 + half * 16 + fr;
#pragma unroll
      for (int rr = 0; rr < 4; rr++) {
        const int r = rb2 + rr;
        const float bd = bf2f(ring[wave][g * 4 + rr][r & 63]);
        const bool valid = ((unsigned)r <= 512u) && (sa <= smax);
        sc[half][rr] = valid ? (acc[rr] + bd) * 0.125f : -1e30f;
      }
    }
    if (first) {
      f32x4 cm;
#pragma unroll
      for (int rr = 0; rr < 4; rr++) cm[rr] = fmaxf(sc[0][rr], sc[1][rr]);
#pragma unroll
      for (int off = 8; off; off >>= 1)
#pragma unroll
        for (int rr = 0; rr < 4; rr++) cm[rr] = fmaxf(cm[rr], __shfl_xor(cm[rr], off));
#pragma unroll
      for (int rr = 0; rr < 4; rr++) m4[rr] = cm[rr];
    } else {
      bool rise = false;
#pragma unroll
      for (int rr = 0; rr < 4; rr++)
        rise |= (fmaxf(sc[0][rr], sc[1][rr]) > m4[rr] + 8.f);
      if (__any(rise)) {
        f32x4 cm;
#pragma unroll
        for (int rr = 0; rr < 4; rr++) cm[rr] = fmaxf(sc[0][rr], sc[1][rr]);
#pragma unroll
        for (int off = 8; off; off >>= 1)
#pragma unroll
          for (int rr = 0; rr < 4; rr++) cm[rr] = fmaxf(cm[rr], __shfl_xor(cm[rr], off));
#pragma unroll
        for (int rr = 0; rr < 4; rr++) {
          const float nm = fmaxf(m4[rr], cm[rr]);
          const float esc = __expf(m4[rr] - nm);
          m4[rr] = nm;
          l4[rr] *= esc;
#pragma unroll
          for (int n = 0; n < 4; n++) oacc[n][rr] *= esc;
        }
      }
    }
    f32x4 pA, pB;
#pragma unroll
    for (int rr = 0; rr < 4; rr++) {
      pA[rr] = __expf(sc[0][rr] - m4[rr]);
      pB[rr] = __expf(sc[1][rr] - m4[rr]);
      l4[rr] += pA[rr] + pB[rr];
    }
#pragma unroll
    for (int rr = 0; rr < 4; rr++) {
      Pl[wave][g * 4 + rr][fr]      = f2bf(pA[rr]);
      Pl[wave][g * 4 + rr][16 + fr] = f2bf(pB[rr]);
    }
    bf16x8 pf = *(const bf16x8*)&Pl[wave][fr][g * 8];
    __builtin_amdgcn_s_setprio(1);
#pragma unroll
    for (int n = 0; n < 4; n++)
      oacc[n] = __builtin_amdgcn_mfma_f32_16x16x32_bf16(pf, vU[n], oacc[n], 0, 0, 0);
    __builtin_amdgcn_s_setprio(0);
    return true;
  };

  bool cont = body(0, kA, vA, kB, vB, true);
  for (int ch = 1; ch < 17 && cont; ch += 2) {
    cont = body(ch, kB, vB, kA, vA, false);
    if (!cont || ch + 1 >= 17) break;
    cont = body(ch + 1, kA, vA, kB, vB, false);
  }

#pragma unroll
  for (int off = 8; off; off >>= 1)
#pragma unroll
    for (int rr = 0; rr < 4; rr++) l4[rr] += __shfl_xor(l4[rr], off);
#pragma unroll
  for (int rr = 0; rr < 4; rr++) {
    const float inv = 1.f / l4[rr];
    const size_t rowo = (size_t)(i0 + sbase + g * 4 + rr) * D_ + hD;
#pragma unroll
    for (int n = 0; n < 4; n++)
      attb[rowo + n * 16 + fr] = f2bf(oacc[n][rr] * inv);
  }
}

// ---------------- residual + LayerNorm (2 or 3 addends) ----------------
__global__ __launch_bounds__(256)
void ln_kernel(const float* __restrict__ a, const float* __restrict__ b,
               const float* __restrict__ c,
               const float* __restrict__ gamma, const float* __restrict__ beta,
               float* __restrict__ outf, ushort* __restrict__ outb) {
  const int row = blockIdx.x;
  const int tid = threadIdx.x;
  const int wave = tid >> 6, lane = tid & 63;
  float4 va = ((const float4*)(a + (size_t)row * D_))[tid];
  float4 vb4 = ((const float4*)(b + (size_t)row * D_))[tid];
  float4 xv;
  xv.x = va.x + vb4.x; xv.y = va.y + vb4.y; xv.z = va.z + vb4.z; xv.w = va.w + vb4.w;
  if (c) {
    float4 vc = ((const float4*)(c + (size_t)row * D_))[tid];
    xv.x += vc.x; xv.y += vc.y; xv.z += vc.z; xv.w += vc.w;
  }
  float s = xv.x + xv.y + xv.z + xv.w;
  float q = xv.x * xv.x + xv.y * xv.y + xv.z * xv.z + xv.w * xv.w;
#pragma unroll
  for (int off = 32; off; off >>= 1) { s += __shfl_xor(s, off); q += __shfl_xor(q, off); }
  __shared__ float red[8];
  if (lane == 0) { red[wave * 2] = s; red[wave * 2 + 1] = q; }
  __syncthreads();
  float ts = red[0] + red[2] + red[4] + red[6];
  float tq = red[1] + red[3] + red[5] + red[7];
  float mu = ts * (1.f / D_);
  float var = tq * (1.f / D_) - mu * mu;
  float rs = rsqrtf(var + 1e-5f);
  float4 g4 = ((const float4*)gamma)[tid];
  float4 be4 = ((const float4*)beta)[tid];
  float4 y;
  y.x = (xv.x - mu) * rs * g4.x + be4.x;
  y.y = (xv.y - mu) * rs * g4.y + be4.y;
  y.z = (xv.z - mu) * rs * g4.z + be4.z;
  y.w = (xv.w - mu) * rs * g4.w + be4.w;
  ((float4*)(outf + (size_t)row * D_))[tid] = y;
  if (outb) ((ushort4*)(outb + (size_t)row * D_))[tid] = pack4(y);
}

extern "C" void kernel_launch(void* const* d_in, const int* in_sizes, int n_in,
                              void* d_out, int out_size, void* d_ws, size_t ws_size,
                              hipStream_t stream) {
  const float* x    = (const float*)d_in[0];
  const float* mem  = (const float*)d_in[1];
  const float* Wq   = (const float*)d_in[2];
  const float* Wk   = (const float*)d_in[3];
  const float* Wv   = (const float*)d_in[4];
  const float* Wo   = (const float*)d_in[5];
  const float* Wr   = (const float*)d_in[6];
  const float* u    = (const float*)d_in[7];
  const float* v    = (const float*)d_in[8];
  const float* ln1g = (const float*)d_in[9];
  const float* ln1b = (const float*)d_in[10];
  const float* W1   = (const float*)d_in[11];
  const float* b1   = (const float*)d_in[12];
  const float* W2   = (const float*)d_in[13];
  const float* b2   = (const float*)d_in[14];
  const float* ln2g = (const float*)d_in[15];
  const float* ln2b = (const float*)d_in[16];
  float* out = (float*)d_out;

  char* ws = (char*)d_ws;
  size_t off = 0;
  auto take = [&](size_t n) { char* p = ws + off; off += (n + 255) & ~(size_t)255; return p; };

  ushort* WqT = (ushort*)take(2097152);
  ushort* WkT = (ushort*)take(2097152);   // WkT||WvT contiguous = [2048][1024]
  ushort* WvT = (ushort*)take(2097152);
  ushort* WoT = (ushort*)take(2097152);
  ushort* WrT = (ushort*)take(2097152);
  ushort* W1T = (ushort*)take(8388608);   // [4096][1024]
  ushort* W2T = (ushort*)take(8388608);   // [1024][4096]

  char* regA = take(8388608);             // kvb + remb; later reused for fbuf
  ushort* kvb  = (ushort*)regA;
  ushort* remb = (ushort*)(regA + 5242880);
  float*  fbuf = (float*)regA;            // FFN2 z0 (+bias)

  char* regB = take(20185088);            // qb,kb,Vt,Rb,attb; overlays: o2b, g
  ushort* qb   = (ushort*)regB;
  ushort* kb   = (ushort*)(regB + 4194304);
  ushort* Vt   = (ushort*)(regB + 9437184);           // [1024][2560]
  ushort* Rb   = (ushort*)(regB + 14680064);
  ushort* attb = (ushort*)(regB + 15990784);
  float*  o2b  = (float*)regB;                        // Wo z=1 partial
  ushort* g    = (ushort*)regB;                       // FFN1 out (16MB)

  float*  o2 = (float*)take(8388608);     // Wo z=0 partial; later FFN2 z1 partial
  float*  h  = (float*)take(8388608);
  ushort* hb = (ushort*)take(4194304);

  prep_kernel<<<17152, 256, 0, stream>>>(x, mem, Wq, Wk, Wv, Wo, Wr, W1, W2,
                                         WqT, WkT, WvT, WoT, WrT, W1T, W2T, kvb, remb);

  proj8p<<<244, 512, 98304, stream>>>(kvb, WqT, WkT, WrT, remb, qb, kb, Vt, Rb);

  attn_mfma4<<<512, 256, 0, stream>>>(qb, kb, Vt, Rb, u, v, attb);

  gemm_kern<64, 128, 1, 2><<<512, 256, 0, stream>>>(attb, WoT, o2, o2b, nullptr,
                                                    2048, 1024, 512, 1024, 8);
  ln_kernel<<<2048, 256, 0, stream>>>(x, o2, o2b, ln1g, ln1b, h, hb);

  // FFN1: 8-phase 128x256, 256 blocks (full chip), 96KB dynamic LDS
  gemm8p2_kern<2><<<256, 512, 98304, stream>>>(hb, W1T, g, nullptr, b1,
                                               2048, 4096, 1024, 1024, 16);

  gemm_kern<64, 128, 3, 2><<<512, 256, 0, stream>>>(g, W2T, fbuf, o2, b2,
                                                    2048, 1024, 2048, 4096, 8);
  ln_kernel<<<2048, 256, 0, stream>>>(h, fbuf, o2, ln2g, ln2b, out, nullptr);
}

// Round 13
// 189.328 us; speedup vs baseline: 1.5742x; 1.1033x over previous
//
#include <hip/hip_runtime.h>
#include <hip/hip_bf16.h>
#include <cstdint>

#define S_ 2048
#define M_ 512
#define L_ 2560
#define D_ 1024
#define F_ 4096
#define H_ 16
#define DH_ 64
#define W_ 256
#define NR_ 513
#define NRP_ 640

typedef unsigned int uint32;
typedef __attribute__((ext_vector_type(8))) short bf16x8;
typedef __attribute__((ext_vector_type(4))) float f32x4;

__device__ __forceinline__ ushort f2bf(float f) {
  uint32 u = __builtin_bit_cast(uint32, f);
  u += 0x7FFFu + ((u >> 16) & 1u);
  return (ushort)(u >> 16);
}
__device__ __forceinline__ float bf2f(ushort s) {
  uint32 u = ((uint32)s) << 16;
  return __builtin_bit_cast(float, u);
}
__device__ __forceinline__ ushort4 pack4(float4 vf) {
  ushort4 r;
  r.x = f2bf(vf.x); r.y = f2bf(vf.y); r.z = f2bf(vf.z); r.w = f2bf(vf.w);
  return r;
}
__device__ __forceinline__ float gelu_tanh(float x) {
  float t = 0.7978845608028654f * x * (1.f + 0.044715f * x * x);
  float e = __expf(2.f * t);
  float th = 1.f - 2.f / (e + 1.f);
  return 0.5f * x * (1.f + th);
}

// async global(16B/lane) -> LDS, wave-uniform LDS base + lane*16
__device__ __forceinline__ void gld_lds16(const ushort* g, ushort* l) {
  __builtin_amdgcn_global_load_lds((const __attribute__((address_space(1))) void*)g,
                                   (__attribute__((address_space(3))) void*)l, 16, 0, 0);
}

// ================= fused prep: 7 weight transposes + kv pack + sinusoid =================
__device__ __forceinline__ void tr_tile(const float* __restrict__ in, ushort* __restrict__ out,
                                        int R, int C, int c0, int r0, int tx, int ty,
                                        float (*tile)[33]) {
#pragma unroll
  for (int i = 0; i < 4; i++)
    tile[ty + i * 8][tx] = in[(size_t)(r0 + ty + i * 8) * C + c0 + tx];
  __syncthreads();
#pragma unroll
  for (int i = 0; i < 4; i++)
    out[(size_t)(c0 + ty + i * 8) * R + r0 + tx] = f2bf(tile[tx][ty + i * 8]);
}

__global__ __launch_bounds__(256)
void prep_kernel(const float* __restrict__ x, const float* __restrict__ mem,
                 const float* __restrict__ Wq, const float* __restrict__ Wk,
                 const float* __restrict__ Wv, const float* __restrict__ Wo,
                 const float* __restrict__ Wr, const float* __restrict__ W1,
                 const float* __restrict__ W2,
                 ushort* __restrict__ WqT, ushort* __restrict__ WkT,
                 ushort* __restrict__ WvT, ushort* __restrict__ WoT,
                 ushort* __restrict__ WrT, ushort* __restrict__ W1T,
                 ushort* __restrict__ W2T,
                 ushort* __restrict__ kvb, ushort* __restrict__ remb) {
  __shared__ float tile[32][33];
  const int bid = blockIdx.x;
  const int tid = threadIdx.x;
  const int tx = tid & 31, ty = tid >> 5;

  if (bid < 5120) {
    const int which = bid >> 10, idx = bid & 1023;
    const float* ins[5] = {Wq, Wk, Wv, Wo, Wr};
    ushort* outs[5] = {WqT, WkT, WvT, WoT, WrT};
    tr_tile(ins[which], outs[which], 1024, 1024, (idx & 31) * 32, (idx >> 5) * 32, tx, ty, tile);
  } else if (bid < 9216) {
    const int idx = bid - 5120;
    tr_tile(W1, W1T, 1024, 4096, (idx % 128) * 32, (idx / 128) * 32, tx, ty, tile);
  } else if (bid < 13312) {
    const int idx = bid - 9216;
    tr_tile(W2, W2T, 4096, 1024, (idx & 31) * 32, (idx >> 5) * 32, tx, ty, tile);
  } else if (bid < 15872) {
    const int k = (bid - 13312) * 256 + tid;
    const int l = k >> 8, c = k & 255;
    const float4* src = (l < M_) ? (const float4*)(mem + (size_t)l * D_)
                                 : (const float4*)(x + (size_t)(l - M_) * D_);
    ((ushort4*)kvb)[k] = pack4(src[c]);
  } else {
    const int idx = (bid - 15872) * 256 + tid;
    const int r = idx >> 9, f = idx & 511;
    if (r < NR_) {
      float invf = expf(-(float)f * (9.210340371976184f / 512.0f));
      float ang = (float)(r - W_) * invf;
      remb[(size_t)r * D_ + f] = f2bf(sinf(ang));
      remb[(size_t)r * D_ + 512 + f] = f2bf(cosf(ang));
    } else if (r < NRP_) {
      remb[(size_t)r * D_ + f] = 0;
      remb[(size_t)r * D_ + 512 + f] = 0;
    }
  }
}

// ====== 8-phase 128x256 GEMM core (T2+T3+T4+T5) ======
// 8 waves (512 thr). LDS/buf: [A0 8K][A1 8K][B0 16K][B1 16K] = 48KB, 2 bufs = 96KB.
// Phase (QM,QN): A-half QM (64 rows) x B-half QN (128 cols); 8 MFMA + 8 ds_read_b128.
// Stage plan/tile: ph1->B1[t+1], ph2->A1[t+1], ph3->A0[t+2], ph4->B0[t+2].
// Steady-state wait: vmcnt(3) once per tile.
// EPI: 0 bf16; 1 f32 (no bias); 2 bf16 gelu(c+bias); 3 f32 (+bias on z0 only); 5 split kb/Vt.
// SPLITK in {1,2,4}: Ksz = per-z K; bz picks output buffer Cout..Cout4 (z>0 no bias).
template <int EPI, int SPLITK>
__device__ __forceinline__
void gemm8p2_core(const ushort* __restrict__ A, const ushort* __restrict__ BT,
                  void* __restrict__ Cout, void* __restrict__ Cout2,
                  void* __restrict__ Cout3, void* __restrict__ Cout4,
                  const float* __restrict__ bias, int Msz, int Nsz, int Ksz, int Kstride,
                  int gx, int bid, int nwg, char* dyn) {
  const int tid = threadIdx.x;
  const int wave = tid >> 6, lane = tid & 63;
  const int wr = wave >> 2, wc = wave & 3;
  const int fr = lane & 15, gf = lane >> 4;
  const int sl = fr & 7;

  // m204 general bijective XCD swizzle
  const int xcd = bid & 7, idx = bid >> 3;
  const int q = nwg >> 3, r8 = nwg & 7;
  const int swz = (xcd < r8 ? xcd * (q + 1) : r8 * (q + 1) + (xcd - r8) * q) + idx;
  const int gy = Msz / 128;
  const int bx = swz % gx;
  const int rest = swz / gx;
  const int by = rest % gy;
  const int bz = rest / gy;
  const int brow = by * 128, bcol = bx * 256;
  const int koff = (SPLITK > 1) ? bz * Ksz : 0;

  const int nt = Ksz >> 6;

  // staging: thread tid loads row tid>>3, pre-swizzled col-slot (tid&7)^(row&7)
  const int srow = tid >> 3;
  const int scol = ((tid & 7) ^ (srow & 7)) * 8;
  const ushort* Ab = A + (size_t)(brow + srow) * Kstride + koff + scol;
  const ushort* Bb = BT + (size_t)(bcol + srow) * Kstride + koff + scol;

  auto stageA = [&](int t, int qm) {
    gld_lds16(Ab + (size_t)(qm * 64) * Kstride + t * 64,
              (ushort*)(dyn + (t & 1) * 49152 + qm * 8192) + wave * 512);
  };
  auto stageB = [&](int t, int qn) {
#pragma unroll
    for (int j = 0; j < 2; j++)
      gld_lds16(Bb + (size_t)(qn * 128 + j * 64) * Kstride + t * 64,
                (ushort*)(dyn + (t & 1) * 49152 + 16384 + qn * 16384 + j * 8192) + wave * 512);
  };

  // read offsets (bytes): row*128 + ((sigma ^ sl) * 16)
  const int ar0 = (wr * 32 + fr) * 128;
  const int ar1 = (wr * 32 + 16 + fr) * 128;
  const int br0 = (wc * 32 + fr) * 128;
  const int br1 = (wc * 32 + 16 + fr) * 128;
  const int s0 = (gf ^ sl) * 16;
  const int s1 = ((4 + gf) ^ sl) * 16;

  f32x4 acc00[2][2] = {}, acc01[2][2] = {}, acc10[2][2] = {}, acc11[2][2] = {};

  // prologue: tile0 (6 instr) + tile1 A0,B0 (3 instr); drain tile0
  stageA(0, 0); stageB(0, 0); stageB(0, 1); stageA(0, 1);
  stageA(1, 0); stageB(1, 0);
  asm volatile("s_waitcnt vmcnt(3)" ::: "memory");
  __builtin_amdgcn_s_barrier();
  __builtin_amdgcn_sched_barrier(0);

#define PH4(QM, QN, ACC, STAGES, WAITS)                                                 \
  {                                                                                     \
    const char* ab = dyn + cur * 49152 + (QM) * 8192;                                   \
    const char* bb = dyn + cur * 49152 + 16384 + (QN) * 16384;                          \
    bf16x8 a00 = *(const bf16x8*)(ab + ar0 + s0);                                       \
    bf16x8 a10 = *(const bf16x8*)(ab + ar1 + s0);                                       \
    bf16x8 a01 = *(const bf16x8*)(ab + ar0 + s1);                                       \
    bf16x8 a11 = *(const bf16x8*)(ab + ar1 + s1);                                       \
    bf16x8 b00 = *(const bf16x8*)(bb + br0 + s0);                                       \
    bf16x8 b10 = *(const bf16x8*)(bb + br1 + s0);                                       \
    bf16x8 b01 = *(const bf16x8*)(bb + br0 + s1);                                       \
    bf16x8 b11 = *(const bf16x8*)(bb + br1 + s1);                                       \
    STAGES;                                                                             \
    WAITS;                                                                              \
    __builtin_amdgcn_s_barrier();                                                       \
    asm volatile("s_waitcnt lgkmcnt(0)" ::: "memory");                                  \
    __builtin_amdgcn_sched_barrier(0);                                                  \
    __builtin_amdgcn_s_setprio(1);                                                      \
    ACC[0][0] = __builtin_amdgcn_mfma_f32_16x16x32_bf16(a00, b00, ACC[0][0], 0, 0, 0);  \
    ACC[0][1] = __builtin_amdgcn_mfma_f32_16x16x32_bf16(a00, b10, ACC[0][1], 0, 0, 0);  \
    ACC[1][0] = __builtin_amdgcn_mfma_f32_16x16x32_bf16(a10, b00, ACC[1][0], 0, 0, 0);  \
    ACC[1][1] = __builtin_amdgcn_mfma_f32_16x16x32_bf16(a10, b10, ACC[1][1], 0, 0, 0);  \
    ACC[0][0] = __builtin_amdgcn_mfma_f32_16x16x32_bf16(a01, b01, ACC[0][0], 0, 0, 0);  \
    ACC[0][1] = __builtin_amdgcn_mfma_f32_16x16x32_bf16(a01, b11, ACC[0][1], 0, 0, 0);  \
    ACC[1][0] = __builtin_amdgcn_mfma_f32_16x16x32_bf16(a11, b01, ACC[1][0], 0, 0, 0);  \
    ACC[1][1] = __builtin_amdgcn_mfma_f32_16x16x32_bf16(a11, b11, ACC[1][1], 0, 0, 0);  \
    __builtin_amdgcn_s_setprio(0);                                                      \
    __builtin_amdgcn_s_barrier();                                                       \
  }

  for (int t = 0; t < nt; t++) {
    const int cur = t & 1;
    PH4(0, 0, acc00, { if (t + 1 < nt) stageB(t + 1, 1); }, {});
    PH4(0, 1, acc01, { if (t + 1 < nt) stageA(t + 1, 1); }, {});
    PH4(1, 0, acc10, { if (t + 2 < nt) stageA(t + 2, 0); }, {});
    PH4(1, 1, acc11, { if (t + 2 < nt) stageB(t + 2, 0); },
        {
          if (t + 1 < nt) {
            if (t + 2 < nt) asm volatile("s_waitcnt vmcnt(3)" ::: "memory");
            else            asm volatile("s_waitcnt vmcnt(0)" ::: "memory");
          }
        });
  }
#undef PH4

  // epilogue
  const int r4 = gf * 4;
  float* co = (float*)Cout;
  bool addb = (EPI == 3);
  if constexpr (SPLITK >= 2) {
    if (bz == 1) { co = (float*)Cout2; addb = false; }
  }
  if constexpr (SPLITK == 4) {
    if (bz == 2) { co = (float*)Cout3; addb = false; }
    if (bz == 3) { co = (float*)Cout4; addb = false; }
  }
  auto wrq = [&](const f32x4 (&ACC)[2][2], int QM, int QN) {
#pragma unroll
    for (int m = 0; m < 2; m++) {
#pragma unroll
      for (int n = 0; n < 2; n++) {
        const int col = bcol + QN * 128 + wc * 32 + n * 16 + fr;
        const int row0 = brow + QM * 64 + wr * 32 + m * 16 + r4;
        if constexpr (EPI == 5) {
          if (col < 1024) {
#pragma unroll
            for (int r = 0; r < 4; r++)
              ((ushort*)Cout)[(size_t)(row0 + r) * 1024 + col] = f2bf(ACC[m][n][r]);
          } else {
            ushort4 pk;
            pk.x = f2bf(ACC[m][n][0]); pk.y = f2bf(ACC[m][n][1]);
            pk.z = f2bf(ACC[m][n][2]); pk.w = f2bf(ACC[m][n][3]);
            *(ushort4*)((ushort*)Cout2 + (size_t)(col - 1024) * Msz + row0) = pk;
          }
        } else if constexpr (EPI == 0 || EPI == 2) {
#pragma unroll
          for (int r = 0; r < 4; r++) {
            float val = ACC[m][n][r];
            size_t o = (size_t)(row0 + r) * Nsz + col;
            if constexpr (EPI == 2) ((ushort*)Cout)[o] = f2bf(gelu_tanh(val + bias[col]));
            else ((ushort*)Cout)[o] = f2bf(val);
          }
        } else {  // EPI 1 / 3: f32
#pragma unroll
          for (int r = 0; r < 4; r++) {
            float val = ACC[m][n][r];
            co[(size_t)(row0 + r) * Nsz + col] = addb ? val + bias[col] : val;
          }
        }
      }
    }
  };
  wrq(acc00, 0, 0);
  wrq(acc01, 0, 1);
  wrq(acc10, 1, 0);
  wrq(acc11, 1, 1);
}

template <int EPI, int SPLITK>
__global__ __launch_bounds__(512)
void gemm8p2_kern(const ushort* __restrict__ A, const ushort* __restrict__ BT,
                  void* __restrict__ Cout, void* __restrict__ Cout2,
                  void* __restrict__ Cout3, void* __restrict__ Cout4,
                  const float* __restrict__ bias, int Msz, int Nsz, int Ksz, int Kstride,
                  int gx) {
  extern __shared__ __align__(16) char dyn[];
  gemm8p2_core<EPI, SPLITK>(A, BT, Cout, Cout2, Cout3, Cout4, bias,
                            Msz, Nsz, Ksz, Kstride, gx, blockIdx.x, gridDim.x, dyn);
}

// merged Q / KV / R projection on the 8-phase core: 64 + 160 + 20 = 244 blocks
__global__ __launch_bounds__(512)
void proj8p(const ushort* __restrict__ kvb, const ushort* __restrict__ WqT,
            const ushort* __restrict__ WkvT, const ushort* __restrict__ WrT,
            const ushort* __restrict__ remb,
            ushort* __restrict__ qb, ushort* __restrict__ kb,
            ushort* __restrict__ Vt, ushort* __restrict__ Rb) {
  extern __shared__ __align__(16) char dyn[];
  const int bid = blockIdx.x;
  if (bid < 64) {
    gemm8p2_core<0, 1>(kvb + 512 * 1024, WqT, qb, nullptr, nullptr, nullptr, nullptr,
                       2048, 1024, 1024, 1024, 4, bid, 64, dyn);
  } else if (bid < 224) {
    gemm8p2_core<5, 1>(kvb, WkvT, kb, Vt, nullptr, nullptr, nullptr,
                       2560, 2048, 1024, 1024, 8, bid - 64, 160, dyn);
  } else {
    gemm8p2_core<0, 1>(remb, WrT, Rb, nullptr, nullptr, nullptr, nullptr,
                       640, 1024, 1024, 1024, 4, bid - 224, 20, dyn);
  }
}

// ---------------- banded attention v6: lazy-max, per-lane partial l, setprio ----------
__global__ __launch_bounds__(256)
void attn_mfma4(const ushort* __restrict__ qb, const ushort* __restrict__ kb,
                const ushort* __restrict__ Vt, const ushort* __restrict__ Rb,
                const float* __restrict__ ubias, const float* __restrict__ vbias,
                ushort* __restrict__ attb) {
  const int bid = blockIdx.x;
  const int swz = (bid & 7) * 64 + (bid >> 3);
  const int h = swz >> 5;
  const int i0 = (swz & 31) * 64;
  const int tid = threadIdx.x;
  const int wave = tid >> 6, lane = tid & 63;
  const int g = lane >> 4, fr = lane & 15;
  const int hD = h * DH_;

  __shared__ __align__(16) ushort ring[4][16][64];
  __shared__ __align__(16) ushort Pl[4][16][40];

  const int qi = i0 + wave * 16 + fr;
  bf16x8 afu[2], afv[2];
#pragma unroll
  for (int kst = 0; kst < 2; kst++) {
    const int dof = kst * 32 + g * 8;
    bf16x8 qv = *(const bf16x8*)(qb + (size_t)qi * D_ + hD + dof);
    const float* up = ubias + hD + dof;
    const float* vp = vbias + hD + dof;
    bf16x8 au, av;
#pragma unroll
    for (int j = 0; j < 8; j++) {
      float q = bf2f((ushort)qv[j]);
      au[j] = (short)f2bf(q + up[j]);
      av[j] = (short)f2bf(q + vp[j]);
    }
    afu[kst] = au; afv[kst] = av;
  }

  const int jb = 256 + i0;
  const int smax = 2303 - i0;
  const int sbase = wave * 16;

  auto produce = [&](int r0, bf16x8 rf0, bf16x8 rf1) {
    f32x4 acc = {};
    __builtin_amdgcn_s_setprio(1);
    acc = __builtin_amdgcn_mfma_f32_16x16x32_bf16(afv[0], rf0, acc, 0, 0, 0);
    acc = __builtin_amdgcn_mfma_f32_16x16x32_bf16(afv[1], rf1, acc, 0, 0, 0);
    __builtin_amdgcn_s_setprio(0);
#pragma unroll
    for (int rr = 0; rr < 4; rr++)
      ring[wave][g * 4 + rr][(r0 + fr) & 63] = f2bf(acc[rr]);
  };
  auto loadRrow = [&](int row, bf16x8* out0, bf16x8* out1) {
    const int rc = row < 0 ? 0 : row;
    *out0 = *(const bf16x8*)(Rb + (size_t)rc * D_ + hD + g * 8);
    *out1 = *(const bf16x8*)(Rb + (size_t)rc * D_ + hD + 32 + g * 8);
  };
  auto loadK = [&](int ch, bf16x8 (&kp)[2][2]) {
#pragma unroll
    for (int half = 0; half < 2; half++) {
      const int sa = sbase + ch * 32 + half * 16 + fr;
      const int jc = (jb + sa < L_ - 1) ? (jb + sa) : (L_ - 1);
      kp[half][0] = *(const bf16x8*)(kb + (size_t)jc * 1024 + hD + g * 8);
      kp[half][1] = *(const bf16x8*)(kb + (size_t)jc * 1024 + hD + 32 + g * 8);
    }
  };
  auto loadV = [&](int ch, bf16x8 (&vp)[4]) {
    int kc = jb + sbase + ch * 32 + g * 8;
    if (kc > L_ - 8) kc = L_ - 8;
#pragma unroll
    for (int n = 0; n < 4; n++)
      vp[n] = *(const bf16x8*)(Vt + (size_t)(hD + n * 16 + fr) * L_ + kc);
  };

#pragma unroll
  for (int t = 0; t < 3; t++) {
    const int r0 = 480 + t * 16;
    bf16x8 rf0, rf1;
    loadRrow(r0 + fr, &rf0, &rf1);
    produce(r0, rf0, rf1);
  }

  float m4[4], l4[4];
  f32x4 oacc[4] = {};
#pragma unroll
  for (int rr = 0; rr < 4; rr++) { m4[rr] = -1e30f; l4[rr] = 0.f; }

  bf16x8 kA[2][2], vA[4], kB[2][2], vB[4];
  bf16x8 rP0a, rP0b, rP1a, rP1b;
  loadK(0, kA); loadV(0, vA);

  auto body = [&](int ch, bf16x8 (&kU)[2][2], bf16x8 (&vU)[4],
                  bf16x8 (&kP)[2][2], bf16x8 (&vP)[4], bool first) -> bool {
    const int c0 = sbase + ch * 32;
    if (c0 > smax) return false;
    if (!first) {
      const int r0 = 480 - ch * 32;
      produce(r0, rP0a, rP0b);
      produce(r0 + 16, rP1a, rP1b);
    }
    if (ch < 16) {
      const int r0n = 480 - (ch + 1) * 32;
      loadRrow(r0n + fr, &rP0a, &rP0b);
      loadRrow(r0n + 16 + fr, &rP1a, &rP1b);
      loadK(ch + 1, kP);
      loadV(ch + 1, vP);
    }
    f32x4 sc[2];
#pragma unroll
    for (int half = 0; half < 2; half++) {
      f32x4 acc = {};
      __builtin_amdgcn_s_setprio(1);
      acc = __builtin_amdgcn_mfma_f32_16x16x32_bf16(afu[0], kU[half][0], acc, 0, 0, 0);
      acc = __builtin_amdgcn_mfma_f32_16x16x32_bf16(afu[1], kU[half][1], acc, 0, 0, 0);
      __builtin_amdgcn_s_setprio(0);
      const int rb2 = 512 + g * 4 - (ch * 32 + half * 16 + fr);
      const int sa = c0 + half * 16 + fr;
#pragma unroll
      for (int rr = 0; rr < 4; rr++) {
        const int r = rb2 + rr;
        const float bd = bf2f(ring[wave][g * 4 + rr][r & 63]);
        const bool valid = ((unsigned)r <= 512u) && (sa <= smax);
        sc[half][rr] = valid ? (acc[rr] + bd) * 0.125f : -1e30f;
      }
    }
    if (first) {
      f32x4 cm;
#pragma unroll
      for (int rr = 0; rr < 4; rr++) cm[rr] = fmaxf(sc[0][rr], sc[1][rr]);
#pragma unroll
      for (int off = 8; off; off >>= 1)
#pragma unroll
        for (int rr = 0; rr < 4; rr++) cm[rr] = fmaxf(cm[rr], __shfl_xor(cm[rr], off));
#pragma unroll
      for (int rr = 0; rr < 4; rr++) m4[rr] = cm[rr];
    } else {
      bool rise = false;
#pragma unroll
      for (int rr = 0; rr < 4; rr++)
        rise |= (fmaxf(sc[0][rr], sc[1][rr]) > m4[rr] + 8.f);
      if (__any(rise)) {
        f32x4 cm;
#pragma unroll
        for (int rr = 0; rr < 4; rr++) cm[rr] = fmaxf(sc[0][rr], sc[1][rr]);
#pragma unroll
        for (int off = 8; off; off >>= 1)
#pragma unroll
          for (int rr = 0; rr < 4; rr++) cm[rr] = fmaxf(cm[rr], __shfl_xor(cm[rr], off));
#pragma unroll
        for (int rr = 0; rr < 4; rr++) {
          const float nm = fmaxf(m4[rr], cm[rr]);
          const float esc = __expf(m4[rr] - nm);
          m4[rr] = nm;
          l4[rr] *= esc;
#pragma unroll
          for (int n = 0; n < 4; n++) oacc[n][rr] *= esc;
        }
      }
    }
    f32x4 pA, pB;
#pragma unroll
    for (int rr = 0; rr < 4; rr++) {
      pA[rr] = __expf(sc[0][rr] - m4[rr]);
      pB[rr] = __expf(sc[1][rr] - m4[rr]);
      l4[rr] += pA[rr] + pB[rr];
    }
#pragma unroll
    for (int rr = 0; rr < 4; rr++) {
      Pl[wave][g * 4 + rr][fr]      = f2bf(pA[rr]);
      Pl[wave][g * 4 + rr][16 + fr] = f2bf(pB[rr]);
    }
    bf16x8 pf = *(const bf16x8*)&Pl[wave][fr][g * 8];
    __builtin_amdgcn_s_setprio(1);
#pragma unroll
    for (int n = 0; n < 4; n++)
      oacc[n] = __builtin_amdgcn_mfma_f32_16x16x32_bf16(pf, vU[n], oacc[n], 0, 0, 0);
    __builtin_amdgcn_s_setprio(0);
    return true;
  };

  bool cont = body(0, kA, vA, kB, vB, true);
  for (int ch = 1; ch < 17 && cont; ch += 2) {
    cont = body(ch, kB, vB, kA, vA, false);
    if (!cont || ch + 1 >= 17) break;
    cont = body(ch + 1, kA, vA, kB, vB, false);
  }

#pragma unroll
  for (int off = 8; off; off >>= 1)
#pragma unroll
    for (int rr = 0; rr < 4; rr++) l4[rr] += __shfl_xor(l4[rr], off);
#pragma unroll
  for (int rr = 0; rr < 4; rr++) {
    const float inv = 1.f / l4[rr];
    const size_t rowo = (size_t)(i0 + sbase + g * 4 + rr) * D_ + hD;
#pragma unroll
    for (int n = 0; n < 4; n++)
      attb[rowo + n * 16 + fr] = f2bf(oacc[n][rr] * inv);
  }
}

// ---------------- residual + LayerNorm (2..5 addends) ----------------
__global__ __launch_bounds__(256)
void ln_kernel(const float* __restrict__ a, const float* __restrict__ b,
               const float* __restrict__ c, const float* __restrict__ d,
               const float* __restrict__ e,
               const float* __restrict__ gamma, const float* __restrict__ beta,
               float* __restrict__ outf, ushort* __restrict__ outb) {
  const int row = blockIdx.x;
  const int tid = threadIdx.x;
  const int wave = tid >> 6, lane = tid & 63;
  float4 va = ((const float4*)(a + (size_t)row * D_))[tid];
  float4 vb4 = ((const float4*)(b + (size_t)row * D_))[tid];
  float4 xv;
  xv.x = va.x + vb4.x; xv.y = va.y + vb4.y; xv.z = va.z + vb4.z; xv.w = va.w + vb4.w;
  if (c) {
    float4 vc = ((const float4*)(c + (size_t)row * D_))[tid];
    xv.x += vc.x; xv.y += vc.y; xv.z += vc.z; xv.w += vc.w;
  }
  if (d) {
    float4 vd = ((const float4*)(d + (size_t)row * D_))[tid];
    xv.x += vd.x; xv.y += vd.y; xv.z += vd.z; xv.w += vd.w;
  }
  if (e) {
    float4 ve = ((const float4*)(e + (size_t)row * D_))[tid];
    xv.x += ve.x; xv.y += ve.y; xv.z += ve.z; xv.w += ve.w;
  }
  float s = xv.x + xv.y + xv.z + xv.w;
  float q = xv.x * xv.x + xv.y * xv.y + xv.z * xv.z + xv.w * xv.w;
#pragma unroll
  for (int off = 32; off; off >>= 1) { s += __shfl_xor(s, off); q += __shfl_xor(q, off); }
  __shared__ float red[8];
  if (lane == 0) { red[wave * 2] = s; red[wave * 2 + 1] = q; }
  __syncthreads();
  float ts = red[0] + red[2] + red[4] + red[6];
  float tq = red[1] + red[3] + red[5] + red[7];
  float mu = ts * (1.f / D_);
  float var = tq * (1.f / D_) - mu * mu;
  float rs = rsqrtf(var + 1e-5f);
  float4 g4 = ((const float4*)gamma)[tid];
  float4 be4 = ((const float4*)beta)[tid];
  float4 y;
  y.x = (xv.x - mu) * rs * g4.x + be4.x;
  y.y = (xv.y - mu) * rs * g4.y + be4.y;
  y.z = (xv.z - mu) * rs * g4.z + be4.z;
  y.w = (xv.w - mu) * rs * g4.w + be4.w;
  ((float4*)(outf + (size_t)row * D_))[tid] = y;
  if (outb) ((ushort4*)(outb + (size_t)row * D_))[tid] = pack4(y);
}

extern "C" void kernel_launch(void* const* d_in, const int* in_sizes, int n_in,
                              void* d_out, int out_size, void* d_ws, size_t ws_size,
                              hipStream_t stream) {
  const float* x    = (const float*)d_in[0];
  const float* mem  = (const float*)d_in[1];
  const float* Wq   = (const float*)d_in[2];
  const float* Wk   = (const float*)d_in[3];
  const float* Wv   = (const float*)d_in[4];
  const float* Wo   = (const float*)d_in[5];
  const float* Wr   = (const float*)d_in[6];
  const float* u    = (const float*)d_in[7];
  const float* v    = (const float*)d_in[8];
  const float* ln1g = (const float*)d_in[9];
  const float* ln1b = (const float*)d_in[10];
  const float* W1   = (const float*)d_in[11];
  const float* b1   = (const float*)d_in[12];
  const float* W2   = (const float*)d_in[13];
  const float* b2   = (const float*)d_in[14];
  const float* ln2g = (const float*)d_in[15];
  const float* ln2b = (const float*)d_in[16];
  float* out = (float*)d_out;

  char* ws = (char*)d_ws;
  size_t off = 0;
  auto take = [&](size_t n) { char* p = ws + off; off += (n + 255) & ~(size_t)255; return p; };

  ushort* WqT = (ushort*)take(2097152);   // dead after proj -> FFN2 z2 partial (8MB spans WqT..WvT)
  ushort* WkT = (ushort*)take(2097152);   // WkT||WvT contiguous = [2048][1024]
  ushort* WvT = (ushort*)take(2097152);
  ushort* WoT = (ushort*)take(2097152);
  ushort* WrT = (ushort*)take(2097152);
  ushort* W1T = (ushort*)take(8388608);   // [4096][1024]; dead after FFN1 -> FFN2 z3 partial
  ushort* W2T = (ushort*)take(8388608);   // [1024][4096]

  char* regA = take(8388608);             // kvb + remb; later reused for fbuf
  ushort* kvb  = (ushort*)regA;
  ushort* remb = (ushort*)(regA + 5242880);
  float*  fbuf = (float*)regA;            // FFN2 z0 (+bias)

  char* regB = take(20185088);            // qb,kb,Vt,Rb,attb; overlays: o2b, g
  ushort* qb   = (ushort*)regB;
  ushort* kb   = (ushort*)(regB + 4194304);
  ushort* Vt   = (ushort*)(regB + 9437184);           // [1024][2560]
  ushort* Rb   = (ushort*)(regB + 14680064);
  ushort* attb = (ushort*)(regB + 15990784);
  float*  o2b  = (float*)regB;                        // Wo z=1 partial
  ushort* g    = (ushort*)regB;                       // FFN1 out (16MB)

  float*  o2 = (float*)take(8388608);     // Wo z=0 partial; later FFN2 z1 partial
  float*  h  = (float*)take(8388608);
  ushort* hb = (ushort*)take(4194304);

  float* p2 = (float*)WqT;                // FFN2 z2 partial (WqT..WvT region)
  float* p3 = (float*)W1T;                // FFN2 z3 partial (W1T region)

  prep_kernel<<<17152, 256, 0, stream>>>(x, mem, Wq, Wk, Wv, Wo, Wr, W1, W2,
                                         WqT, WkT, WvT, WoT, WrT, W1T, W2T, kvb, remb);

  proj8p<<<244, 512, 98304, stream>>>(kvb, WqT, WkT, WrT, remb, qb, kb, Vt, Rb);

  attn_mfma4<<<512, 256, 0, stream>>>(qb, kb, Vt, Rb, u, v, attb);

  // Wo: 8-phase SK2, 128 blocks (z0->o2, z1->o2b)
  gemm8p2_kern<1, 2><<<128, 512, 98304, stream>>>(attb, WoT, o2, o2b, nullptr, nullptr,
                                                  nullptr, 2048, 1024, 512, 1024, 4);
  ln_kernel<<<2048, 256, 0, stream>>>(x, o2, o2b, nullptr, nullptr, ln1g, ln1b, h, hb);

  // FFN1: 8-phase 128x256, 256 blocks (full chip)
  gemm8p2_kern<2, 1><<<256, 512, 98304, stream>>>(hb, W1T, g, nullptr, nullptr, nullptr,
                                                  b1, 2048, 4096, 1024, 1024, 16);

  // FFN2: 8-phase SK4, 256 blocks (z0->fbuf(+b2), z1->o2, z2->p2, z3->p3)
  gemm8p2_kern<3, 4><<<256, 512, 98304, stream>>>(g, W2T, fbuf, o2, p2, p3,
                                                  b2, 2048, 1024, 1024, 4096, 4);
  ln_kernel<<<2048, 256, 0, stream>>>(h, fbuf, o2, p2, p3, ln2g, ln2b, out, nullptr);
}

// Round 14
// 187.866 us; speedup vs baseline: 1.5864x; 1.0078x over previous
//
#include <hip/hip_runtime.h>
#include <hip/hip_bf16.h>
#include <cstdint>

#define S_ 2048
#define M_ 512
#define L_ 2560
#define D_ 1024
#define F_ 4096
#define H_ 16
#define DH_ 64
#define W_ 256
#define NR_ 513
#define NRP_ 640

typedef unsigned int uint32;
typedef __attribute__((ext_vector_type(8))) short bf16x8;
typedef __attribute__((ext_vector_type(4))) float f32x4;

__device__ __forceinline__ ushort f2bf(float f) {
  uint32 u = __builtin_bit_cast(uint32, f);
  u += 0x7FFFu + ((u >> 16) & 1u);
  return (ushort)(u >> 16);
}
__device__ __forceinline__ float bf2f(ushort s) {
  uint32 u = ((uint32)s) << 16;
  return __builtin_bit_cast(float, u);
}
__device__ __forceinline__ ushort4 pack4(float4 vf) {
  ushort4 r;
  r.x = f2bf(vf.x); r.y = f2bf(vf.y); r.z = f2bf(vf.z); r.w = f2bf(vf.w);
  return r;
}
__device__ __forceinline__ float gelu_tanh(float x) {
  float t = 0.7978845608028654f * x * (1.f + 0.044715f * x * x);
  float e = __expf(2.f * t);
  float th = 1.f - 2.f / (e + 1.f);
  return 0.5f * x * (1.f + th);
}

// async global(16B/lane) -> LDS, wave-uniform LDS base + lane*16
__device__ __forceinline__ void gld_lds16(const ushort* g, ushort* l) {
  __builtin_amdgcn_global_load_lds((const __attribute__((address_space(1))) void*)g,
                                   (__attribute__((address_space(3))) void*)l, 16, 0, 0);
}

// ================= fused prep: 7 weight transposes + kv pack + sinusoid =================
__device__ __forceinline__ void tr_tile(const float* __restrict__ in, ushort* __restrict__ out,
                                        int R, int C, int c0, int r0, int tx, int ty,
                                        float (*tile)[33]) {
#pragma unroll
  for (int i = 0; i < 4; i++)
    tile[ty + i * 8][tx] = in[(size_t)(r0 + ty + i * 8) * C + c0 + tx];
  __syncthreads();
#pragma unroll
  for (int i = 0; i < 4; i++)
    out[(size_t)(c0 + ty + i * 8) * R + r0 + tx] = f2bf(tile[tx][ty + i * 8]);
}

__global__ __launch_bounds__(256)
void prep_kernel(const float* __restrict__ x, const float* __restrict__ mem,
                 const float* __restrict__ Wq, const float* __restrict__ Wk,
                 const float* __restrict__ Wv, const float* __restrict__ Wo,
                 const float* __restrict__ Wr, const float* __restrict__ W1,
                 const float* __restrict__ W2,
                 ushort* __restrict__ WqT, ushort* __restrict__ WkT,
                 ushort* __restrict__ WvT, ushort* __restrict__ WoT,
                 ushort* __restrict__ WrT, ushort* __restrict__ W1T,
                 ushort* __restrict__ W2T,
                 ushort* __restrict__ kvb, ushort* __restrict__ remb) {
  __shared__ float tile[32][33];
  const int bid = blockIdx.x;
  const int tid = threadIdx.x;
  const int tx = tid & 31, ty = tid >> 5;

  if (bid < 5120) {
    const int which = bid >> 10, idx = bid & 1023;
    const float* ins[5] = {Wq, Wk, Wv, Wo, Wr};
    ushort* outs[5] = {WqT, WkT, WvT, WoT, WrT};
    tr_tile(ins[which], outs[which], 1024, 1024, (idx & 31) * 32, (idx >> 5) * 32, tx, ty, tile);
  } else if (bid < 9216) {
    const int idx = bid - 5120;
    tr_tile(W1, W1T, 1024, 4096, (idx % 128) * 32, (idx / 128) * 32, tx, ty, tile);
  } else if (bid < 13312) {
    const int idx = bid - 9216;
    tr_tile(W2, W2T, 4096, 1024, (idx & 31) * 32, (idx >> 5) * 32, tx, ty, tile);
  } else if (bid < 15872) {
    const int k = (bid - 13312) * 256 + tid;
    const int l = k >> 8, c = k & 255;
    const float4* src = (l < M_) ? (const float4*)(mem + (size_t)l * D_)
                                 : (const float4*)(x + (size_t)(l - M_) * D_);
    ((ushort4*)kvb)[k] = pack4(src[c]);
  } else {
    const int idx = (bid - 15872) * 256 + tid;
    const int r = idx >> 9, f = idx & 511;
    if (r < NR_) {
      float invf = expf(-(float)f * (9.210340371976184f / 512.0f));
      float ang = (float)(r - W_) * invf;
      remb[(size_t)r * D_ + f] = f2bf(sinf(ang));
      remb[(size_t)r * D_ + 512 + f] = f2bf(cosf(ang));
    } else if (r < NRP_) {
      remb[(size_t)r * D_ + f] = 0;
      remb[(size_t)r * D_ + 512 + f] = 0;
    }
  }
}

// ====== 8-phase 128x256 GEMM core (T2+T3+T4+T5) ======
template <int EPI, int SPLITK>
__device__ __forceinline__
void gemm8p2_core(const ushort* __restrict__ A, const ushort* __restrict__ BT,
                  void* __restrict__ Cout, void* __restrict__ Cout2,
                  void* __restrict__ Cout3, void* __restrict__ Cout4,
                  const float* __restrict__ bias, int Msz, int Nsz, int Ksz, int Kstride,
                  int gx, int bid, int nwg, char* dyn) {
  const int tid = threadIdx.x;
  const int wave = tid >> 6, lane = tid & 63;
  const int wr = wave >> 2, wc = wave & 3;
  const int fr = lane & 15, gf = lane >> 4;
  const int sl = fr & 7;

  // m204 general bijective XCD swizzle
  const int xcd = bid & 7, idx = bid >> 3;
  const int q = nwg >> 3, r8 = nwg & 7;
  const int swz = (xcd < r8 ? xcd * (q + 1) : r8 * (q + 1) + (xcd - r8) * q) + idx;
  const int gy = Msz / 128;
  const int bx = swz % gx;
  const int rest = swz / gx;
  const int by = rest % gy;
  const int bz = rest / gy;
  const int brow = by * 128, bcol = bx * 256;
  const int koff = (SPLITK > 1) ? bz * Ksz : 0;

  const int nt = Ksz >> 6;

  const int srow = tid >> 3;
  const int scol = ((tid & 7) ^ (srow & 7)) * 8;
  const ushort* Ab = A + (size_t)(brow + srow) * Kstride + koff + scol;
  const ushort* Bb = BT + (size_t)(bcol + srow) * Kstride + koff + scol;

  auto stageA = [&](int t, int qm) {
    gld_lds16(Ab + (size_t)(qm * 64) * Kstride + t * 64,
              (ushort*)(dyn + (t & 1) * 49152 + qm * 8192) + wave * 512);
  };
  auto stageB = [&](int t, int qn) {
#pragma unroll
    for (int j = 0; j < 2; j++)
      gld_lds16(Bb + (size_t)(qn * 128 + j * 64) * Kstride + t * 64,
                (ushort*)(dyn + (t & 1) * 49152 + 16384 + qn * 16384 + j * 8192) + wave * 512);
  };

  const int ar0 = (wr * 32 + fr) * 128;
  const int ar1 = (wr * 32 + 16 + fr) * 128;
  const int br0 = (wc * 32 + fr) * 128;
  const int br1 = (wc * 32 + 16 + fr) * 128;
  const int s0 = (gf ^ sl) * 16;
  const int s1 = ((4 + gf) ^ sl) * 16;

  f32x4 acc00[2][2] = {}, acc01[2][2] = {}, acc10[2][2] = {}, acc11[2][2] = {};

  stageA(0, 0); stageB(0, 0); stageB(0, 1); stageA(0, 1);
  stageA(1, 0); stageB(1, 0);
  asm volatile("s_waitcnt vmcnt(3)" ::: "memory");
  __builtin_amdgcn_s_barrier();
  __builtin_amdgcn_sched_barrier(0);

#define PH4(QM, QN, ACC, STAGES, WAITS)                                                 \
  {                                                                                     \
    const char* ab = dyn + cur * 49152 + (QM) * 8192;                                   \
    const char* bb = dyn + cur * 49152 + 16384 + (QN) * 16384;                          \
    bf16x8 a00 = *(const bf16x8*)(ab + ar0 + s0);                                       \
    bf16x8 a10 = *(const bf16x8*)(ab + ar1 + s0);                                       \
    bf16x8 a01 = *(const bf16x8*)(ab + ar0 + s1);                                       \
    bf16x8 a11 = *(const bf16x8*)(ab + ar1 + s1);                                       \
    bf16x8 b00 = *(const bf16x8*)(bb + br0 + s0);                                       \
    bf16x8 b10 = *(const bf16x8*)(bb + br1 + s0);                                       \
    bf16x8 b01 = *(const bf16x8*)(bb + br0 + s1);                                       \
    bf16x8 b11 = *(const bf16x8*)(bb + br1 + s1);                                       \
    STAGES;                                                                             \
    WAITS;                                                                              \
    __builtin_amdgcn_s_barrier();                                                       \
    asm volatile("s_waitcnt lgkmcnt(0)" ::: "memory");                                  \
    __builtin_amdgcn_sched_barrier(0);                                                  \
    __builtin_amdgcn_s_setprio(1);                                                      \
    ACC[0][0] = __builtin_amdgcn_mfma_f32_16x16x32_bf16(a00, b00, ACC[0][0], 0, 0, 0);  \
    ACC[0][1] = __builtin_amdgcn_mfma_f32_16x16x32_bf16(a00, b10, ACC[0][1], 0, 0, 0);  \
    ACC[1][0] = __builtin_amdgcn_mfma_f32_16x16x32_bf16(a10, b00, ACC[1][0], 0, 0, 0);  \
    ACC[1][1] = __builtin_amdgcn_mfma_f32_16x16x32_bf16(a10, b10, ACC[1][1], 0, 0, 0);  \
    ACC[0][0] = __builtin_amdgcn_mfma_f32_16x16x32_bf16(a01, b01, ACC[0][0], 0, 0, 0);  \
    ACC[0][1] = __builtin_amdgcn_mfma_f32_16x16x32_bf16(a01, b11, ACC[0][1], 0, 0, 0);  \
    ACC[1][0] = __builtin_amdgcn_mfma_f32_16x16x32_bf16(a11, b01, ACC[1][0], 0, 0, 0);  \
    ACC[1][1] = __builtin_amdgcn_mfma_f32_16x16x32_bf16(a11, b11, ACC[1][1], 0, 0, 0);  \
    __builtin_amdgcn_s_setprio(0);                                                      \
    __builtin_amdgcn_s_barrier();                                                       \
  }

  for (int t = 0; t < nt; t++) {
    const int cur = t & 1;
    PH4(0, 0, acc00, { if (t + 1 < nt) stageB(t + 1, 1); }, {});
    PH4(0, 1, acc01, { if (t + 1 < nt) stageA(t + 1, 1); }, {});
    PH4(1, 0, acc10, { if (t + 2 < nt) stageA(t + 2, 0); }, {});
    PH4(1, 1, acc11, { if (t + 2 < nt) stageB(t + 2, 0); },
        {
          if (t + 1 < nt) {
            if (t + 2 < nt) asm volatile("s_waitcnt vmcnt(3)" ::: "memory");
            else            asm volatile("s_waitcnt vmcnt(0)" ::: "memory");
          }
        });
  }
#undef PH4

  const int r4 = gf * 4;
  float* co = (float*)Cout;
  bool addb = (EPI == 3);
  if constexpr (SPLITK >= 2) {
    if (bz == 1) { co = (float*)Cout2; addb = false; }
  }
  if constexpr (SPLITK == 4) {
    if (bz == 2) { co = (float*)Cout3; addb = false; }
    if (bz == 3) { co = (float*)Cout4; addb = false; }
  }
  auto wrq = [&](const f32x4 (&ACC)[2][2], int QM, int QN) {
#pragma unroll
    for (int m = 0; m < 2; m++) {
#pragma unroll
      for (int n = 0; n < 2; n++) {
        const int col = bcol + QN * 128 + wc * 32 + n * 16 + fr;
        const int row0 = brow + QM * 64 + wr * 32 + m * 16 + r4;
        if constexpr (EPI == 5) {
          if (col < 1024) {
#pragma unroll
            for (int r = 0; r < 4; r++)
              ((ushort*)Cout)[(size_t)(row0 + r) * 1024 + col] = f2bf(ACC[m][n][r]);
          } else {
            ushort4 pk;
            pk.x = f2bf(ACC[m][n][0]); pk.y = f2bf(ACC[m][n][1]);
            pk.z = f2bf(ACC[m][n][2]); pk.w = f2bf(ACC[m][n][3]);
            *(ushort4*)((ushort*)Cout2 + (size_t)(col - 1024) * Msz + row0) = pk;
          }
        } else if constexpr (EPI == 0 || EPI == 2) {
#pragma unroll
          for (int r = 0; r < 4; r++) {
            float val = ACC[m][n][r];
            size_t o = (size_t)(row0 + r) * Nsz + col;
            if constexpr (EPI == 2) ((ushort*)Cout)[o] = f2bf(gelu_tanh(val + bias[col]));
            else ((ushort*)Cout)[o] = f2bf(val);
          }
        } else {
#pragma unroll
          for (int r = 0; r < 4; r++) {
            float val = ACC[m][n][r];
            co[(size_t)(row0 + r) * Nsz + col] = addb ? val + bias[col] : val;
          }
        }
      }
    }
  };
  wrq(acc00, 0, 0);
  wrq(acc01, 0, 1);
  wrq(acc10, 1, 0);
  wrq(acc11, 1, 1);
}

template <int EPI, int SPLITK>
__global__ __launch_bounds__(512)
void gemm8p2_kern(const ushort* __restrict__ A, const ushort* __restrict__ BT,
                  void* __restrict__ Cout, void* __restrict__ Cout2,
                  void* __restrict__ Cout3, void* __restrict__ Cout4,
                  const float* __restrict__ bias, int Msz, int Nsz, int Ksz, int Kstride,
                  int gx) {
  extern __shared__ __align__(16) char dyn[];
  gemm8p2_core<EPI, SPLITK>(A, BT, Cout, Cout2, Cout3, Cout4, bias,
                            Msz, Nsz, Ksz, Kstride, gx, blockIdx.x, gridDim.x, dyn);
}

// merged Q / KV / R projection on the 8-phase core: 64 + 160 + 20 = 244 blocks
__global__ __launch_bounds__(512)
void proj8p(const ushort* __restrict__ kvb, const ushort* __restrict__ WqT,
            const ushort* __restrict__ WkvT, const ushort* __restrict__ WrT,
            const ushort* __restrict__ remb,
            ushort* __restrict__ qb, ushort* __restrict__ kb,
            ushort* __restrict__ Vt, ushort* __restrict__ Rb) {
  extern __shared__ __align__(16) char dyn[];
  const int bid = blockIdx.x;
  if (bid < 64) {
    gemm8p2_core<0, 1>(kvb + 512 * 1024, WqT, qb, nullptr, nullptr, nullptr, nullptr,
                       2048, 1024, 1024, 1024, 4, bid, 64, dyn);
  } else if (bid < 224) {
    gemm8p2_core<5, 1>(kvb, WkvT, kb, Vt, nullptr, nullptr, nullptr,
                       2560, 2048, 1024, 1024, 8, bid - 64, 160, dyn);
  } else {
    gemm8p2_core<0, 1>(remb, WrT, Rb, nullptr, nullptr, nullptr, nullptr,
                       640, 1024, 1024, 1024, 4, bid - 224, 20, dyn);
  }
}

// ---------------- banded attention v7: produce-ahead ring, hidden P round-trip ----------
// Block: 64 queries x 1 head, 4 waves x 16 queries. Ring 128 cols; tiles for chunk c+1
// produced during chunk c (R regs double-buffered); Pl read drains under produce.
__global__ __launch_bounds__(256)
void attn_mfma5(const ushort* __restrict__ qb, const ushort* __restrict__ kb,
                const ushort* __restrict__ Vt, const ushort* __restrict__ Rb,
                const float* __restrict__ ubias, const float* __restrict__ vbias,
                ushort* __restrict__ attb) {
  const int bid = blockIdx.x;
  const int swz = (bid & 7) * 64 + (bid >> 3);
  const int h = swz >> 5;
  const int i0 = (swz & 31) * 64;
  const int tid = threadIdx.x;
  const int wave = tid >> 6, lane = tid & 63;
  const int g = lane >> 4, fr = lane & 15;
  const int hD = h * DH_;

  __shared__ __align__(16) ushort ring[4][16][128];
  __shared__ __align__(16) ushort Pl[4][16][40];

  const int qi = i0 + wave * 16 + fr;
  bf16x8 afu[2], afv[2];
#pragma unroll
  for (int kst = 0; kst < 2; kst++) {
    const int dof = kst * 32 + g * 8;
    bf16x8 qv = *(const bf16x8*)(qb + (size_t)qi * D_ + hD + dof);
    const float* up = ubias + hD + dof;
    const float* vp = vbias + hD + dof;
    bf16x8 au, av;
#pragma unroll
    for (int j = 0; j < 8; j++) {
      float q = bf2f((ushort)qv[j]);
      au[j] = (short)f2bf(q + up[j]);
      av[j] = (short)f2bf(q + vp[j]);
    }
    afu[kst] = au; afv[kst] = av;
  }

  const int jb = 256 + i0;
  const int smax = 2303 - i0;
  const int sbase = wave * 16;

  auto produce = [&](int r0, bf16x8 rf0, bf16x8 rf1) {
    f32x4 acc = {};
    __builtin_amdgcn_s_setprio(1);
    acc = __builtin_amdgcn_mfma_f32_16x16x32_bf16(afv[0], rf0, acc, 0, 0, 0);
    acc = __builtin_amdgcn_mfma_f32_16x16x32_bf16(afv[1], rf1, acc, 0, 0, 0);
    __builtin_amdgcn_s_setprio(0);
#pragma unroll
    for (int rr = 0; rr < 4; rr++)
      ring[wave][g * 4 + rr][(r0 + fr) & 127] = f2bf(acc[rr]);
  };
  auto loadRrow = [&](int row, bf16x8* out0, bf16x8* out1) {
    const int rc = row < 0 ? 0 : row;
    *out0 = *(const bf16x8*)(Rb + (size_t)rc * D_ + hD + g * 8);
    *out1 = *(const bf16x8*)(Rb + (size_t)rc * D_ + hD + 32 + g * 8);
  };
  auto loadK = [&](int ch, bf16x8 (&kp)[2][2]) {
#pragma unroll
    for (int half = 0; half < 2; half++) {
      const int sa = sbase + ch * 32 + half * 16 + fr;
      const int jc = (jb + sa < L_ - 1) ? (jb + sa) : (L_ - 1);
      kp[half][0] = *(const bf16x8*)(kb + (size_t)jc * 1024 + hD + g * 8);
      kp[half][1] = *(const bf16x8*)(kb + (size_t)jc * 1024 + hD + 32 + g * 8);
    }
  };
  auto loadV = [&](int ch, bf16x8 (&vp)[4]) {
    int kc = jb + sbase + ch * 32 + g * 8;
    if (kc > L_ - 8) kc = L_ - 8;
#pragma unroll
    for (int n = 0; n < 4; n++)
      vp[n] = *(const bf16x8*)(Vt + (size_t)(hD + n * 16 + fr) * L_ + kc);
  };

  // prologue: ring tiles for chunk 0 (rows 480..527)
#pragma unroll
  for (int t = 0; t < 3; t++) {
    const int r0 = 480 + t * 16;
    bf16x8 rf0, rf1;
    loadRrow(r0 + fr, &rf0, &rf1);
    produce(r0, rf0, rf1);
  }

  float m4[4], l4[4];
  f32x4 oacc[4] = {};
#pragma unroll
  for (int rr = 0; rr < 4; rr++) { m4[rr] = -1e30f; l4[rr] = 0.f; }

  bf16x8 kA[2][2], vA[4], kB[2][2], vB[4];
  bf16x8 rA[4], rB[4];   // R fragments for the 2 ring tiles produced this/next chunk
  // preload R regs for tiles produced during chunk 0 (tiles {448,464})
  loadRrow(448 + fr, &rA[0], &rA[1]);
  loadRrow(464 + fr, &rA[2], &rA[3]);
  loadK(0, kA); loadV(0, vA);

  auto body = [&](int ch, bf16x8 (&kU)[2][2], bf16x8 (&vU)[4],
                  bf16x8 (&kP)[2][2], bf16x8 (&vP)[4],
                  bf16x8 (&rU)[4], bf16x8 (&rP)[4], bool first) -> bool {
    const int c0 = sbase + ch * 32;
    if (c0 > smax) return false;
    // AC scores
    f32x4 sc[2];
#pragma unroll
    for (int half = 0; half < 2; half++) {
      f32x4 acc = {};
      __builtin_amdgcn_s_setprio(1);
      acc = __builtin_amdgcn_mfma_f32_16x16x32_bf16(afu[0], kU[half][0], acc, 0, 0, 0);
      acc = __builtin_amdgcn_mfma_f32_16x16x32_bf16(afu[1], kU[half][1], acc, 0, 0, 0);
      __builtin_amdgcn_s_setprio(0);
      sc[half] = acc;
    }
    // prefetch for chunk ch+1 (K/V) and for ch+1's produce (R rows of tiles {416-32ch,432-32ch})
    if (ch < 16) {
      loadK(ch + 1, kP);
      loadV(ch + 1, vP);
    }
    if (ch < 15) {
      loadRrow(416 - ch * 32 + fr, &rP[0], &rP[1]);
      loadRrow(432 - ch * 32 + fr, &rP[2], &rP[3]);
    }
    // BD gather from ring (produced >=1 chunk ago) + mask
#pragma unroll
    for (int half = 0; half < 2; half++) {
      const int rb2 = 512 + g * 4 - (ch * 32 + half * 16 + fr);
      const int sa = c0 + half * 16 + fr;
#pragma unroll
      for (int rr = 0; rr < 4; rr++) {
        const int r = rb2 + rr;
        const float bd = bf2f(ring[wave][g * 4 + rr][r & 127]);
        const bool valid = ((unsigned)r <= 512u) && (sa <= smax);
        sc[half][rr] = valid ? (sc[half][rr] + bd) * 0.125f : -1e30f;
      }
    }
    if (first) {
      f32x4 cm;
#pragma unroll
      for (int rr = 0; rr < 4; rr++) cm[rr] = fmaxf(sc[0][rr], sc[1][rr]);
#pragma unroll
      for (int off = 8; off; off >>= 1)
#pragma unroll
        for (int rr = 0; rr < 4; rr++) cm[rr] = fmaxf(cm[rr], __shfl_xor(cm[rr], off));
#pragma unroll
      for (int rr = 0; rr < 4; rr++) m4[rr] = cm[rr];
    } else {
      bool rise = false;
#pragma unroll
      for (int rr = 0; rr < 4; rr++)
        rise |= (fmaxf(sc[0][rr], sc[1][rr]) > m4[rr] + 8.f);
      if (__any(rise)) {
        f32x4 cm;
#pragma unroll
        for (int rr = 0; rr < 4; rr++) cm[rr] = fmaxf(sc[0][rr], sc[1][rr]);
#pragma unroll
        for (int off = 8; off; off >>= 1)
#pragma unroll
          for (int rr = 0; rr < 4; rr++) cm[rr] = fmaxf(cm[rr], __shfl_xor(cm[rr], off));
#pragma unroll
        for (int rr = 0; rr < 4; rr++) {
          const float nm = fmaxf(m4[rr], cm[rr]);
          const float esc = __expf(m4[rr] - nm);
          m4[rr] = nm;
          l4[rr] *= esc;
#pragma unroll
          for (int n = 0; n < 4; n++) oacc[n][rr] *= esc;
        }
      }
    }
    f32x4 pA, pB;
#pragma unroll
    for (int rr = 0; rr < 4; rr++) {
      pA[rr] = __expf(sc[0][rr] - m4[rr]);
      pB[rr] = __expf(sc[1][rr] - m4[rr]);
      l4[rr] += pA[rr] + pB[rr];
    }
    // P -> LDS; read back; the read's latency drains under the produce below
#pragma unroll
    for (int rr = 0; rr < 4; rr++) {
      Pl[wave][g * 4 + rr][fr]      = f2bf(pA[rr]);
      Pl[wave][g * 4 + rr][16 + fr] = f2bf(pB[rr]);
    }
    bf16x8 pf = *(const bf16x8*)&Pl[wave][fr][g * 8];
    // produce ring tiles for chunk ch+1 (uses R regs loaded during ch-1)
    if (ch < 16) {
      produce(448 - ch * 32, rU[0], rU[1]);
      produce(464 - ch * 32, rU[2], rU[3]);
    }
    // PV
    __builtin_amdgcn_s_setprio(1);
#pragma unroll
    for (int n = 0; n < 4; n++)
      oacc[n] = __builtin_amdgcn_mfma_f32_16x16x32_bf16(pf, vU[n], oacc[n], 0, 0, 0);
    __builtin_amdgcn_s_setprio(0);
    return true;
  };

  bool cont = body(0, kA, vA, kB, vB, rA, rB, true);
  for (int ch = 1; ch < 17 && cont; ch += 2) {
    cont = body(ch, kB, vB, kA, vA, rB, rA, false);
    if (!cont || ch + 1 >= 17) break;
    cont = body(ch + 1, kA, vA, kB, vB, rA, rB, false);
  }

#pragma unroll
  for (int off = 8; off; off >>= 1)
#pragma unroll
    for (int rr = 0; rr < 4; rr++) l4[rr] += __shfl_xor(l4[rr], off);
#pragma unroll
  for (int rr = 0; rr < 4; rr++) {
    const float inv = 1.f / l4[rr];
    const size_t rowo = (size_t)(i0 + sbase + g * 4 + rr) * D_ + hD;
#pragma unroll
    for (int n = 0; n < 4; n++)
      attb[rowo + n * 16 + fr] = f2bf(oacc[n][rr] * inv);
  }
}

// ---------------- residual + LayerNorm (2..5 addends) ----------------
__global__ __launch_bounds__(256)
void ln_kernel(const float* __restrict__ a, const float* __restrict__ b,
               const float* __restrict__ c, const float* __restrict__ d,
               const float* __restrict__ e,
               const float* __restrict__ gamma, const float* __restrict__ beta,
               float* __restrict__ outf, ushort* __restrict__ outb) {
  const int row = blockIdx.x;
  const int tid = threadIdx.x;
  const int wave = tid >> 6, lane = tid & 63;
  float4 va = ((const float4*)(a + (size_t)row * D_))[tid];
  float4 vb4 = ((const float4*)(b + (size_t)row * D_))[tid];
  float4 xv;
  xv.x = va.x + vb4.x; xv.y = va.y + vb4.y; xv.z = va.z + vb4.z; xv.w = va.w + vb4.w;
  if (c) {
    float4 vc = ((const float4*)(c + (size_t)row * D_))[tid];
    xv.x += vc.x; xv.y += vc.y; xv.z += vc.z; xv.w += vc.w;
  }
  if (d) {
    float4 vd = ((const float4*)(d + (size_t)row * D_))[tid];
    xv.x += vd.x; xv.y += vd.y; xv.z += vd.z; xv.w += vd.w;
  }
  if (e) {
    float4 ve = ((const float4*)(e + (size_t)row * D_))[tid];
    xv.x += ve.x; xv.y += ve.y; xv.z += ve.z; xv.w += ve.w;
  }
  float s = xv.x + xv.y + xv.z + xv.w;
  float q = xv.x * xv.x + xv.y * xv.y + xv.z * xv.z + xv.w * xv.w;
#pragma unroll
  for (int off = 32; off; off >>= 1) { s += __shfl_xor(s, off); q += __shfl_xor(q, off); }
  __shared__ float red[8];
  if (lane == 0) { red[wave * 2] = s; red[wave * 2 + 1] = q; }
  __syncthreads();
  float ts = red[0] + red[2] + red[4] + red[6];
  float tq = red[1] + red[3] + red[5] + red[7];
  float mu = ts * (1.f / D_);
  float var = tq * (1.f / D_) - mu * mu;
  float rs = rsqrtf(var + 1e-5f);
  float4 g4 = ((const float4*)gamma)[tid];
  float4 be4 = ((const float4*)beta)[tid];
  float4 y;
  y.x = (xv.x - mu) * rs * g4.x + be4.x;
  y.y = (xv.y - mu) * rs * g4.y + be4.y;
  y.z = (xv.z - mu) * rs * g4.z + be4.z;
  y.w = (xv.w - mu) * rs * g4.w + be4.w;
  ((float4*)(outf + (size_t)row * D_))[tid] = y;
  if (outb) ((ushort4*)(outb + (size_t)row * D_))[tid] = pack4(y);
}

extern "C" void kernel_launch(void* const* d_in, const int* in_sizes, int n_in,
                              void* d_out, int out_size, void* d_ws, size_t ws_size,
                              hipStream_t stream) {
  const float* x    = (const float*)d_in[0];
  const float* mem  = (const float*)d_in[1];
  const float* Wq   = (const float*)d_in[2];
  const float* Wk   = (const float*)d_in[3];
  const float* Wv   = (const float*)d_in[4];
  const float* Wo   = (const float*)d_in[5];
  const float* Wr   = (const float*)d_in[6];
  const float* u    = (const float*)d_in[7];
  const float* v    = (const float*)d_in[8];
  const float* ln1g = (const float*)d_in[9];
  const float* ln1b = (const float*)d_in[10];
  const float* W1   = (const float*)d_in[11];
  const float* b1   = (const float*)d_in[12];
  const float* W2   = (const float*)d_in[13];
  const float* b2   = (const float*)d_in[14];
  const float* ln2g = (const float*)d_in[15];
  const float* ln2b = (const float*)d_in[16];
  float* out = (float*)d_out;

  char* ws = (char*)d_ws;
  size_t off = 0;
  auto take = [&](size_t n) { char* p = ws + off; off += (n + 255) & ~(size_t)255; return p; };

  ushort* WqT = (ushort*)take(2097152);   // dead after proj -> FFN2 z2 partial
  ushort* WkT = (ushort*)take(2097152);   // WkT||WvT contiguous = [2048][1024]
  ushort* WvT = (ushort*)take(2097152);
  ushort* WoT = (ushort*)take(2097152);
  ushort* WrT = (ushort*)take(2097152);
  ushort* W1T = (ushort*)take(8388608);   // dead after FFN1 -> FFN2 z3 partial
  ushort* W2T = (ushort*)take(8388608);

  char* regA = take(8388608);             // kvb + remb; later reused for fbuf
  ushort* kvb  = (ushort*)regA;
  ushort* remb = (ushort*)(regA + 5242880);
  float*  fbuf = (float*)regA;            // FFN2 z0 (+bias)

  char* regB = take(20185088);            // qb,kb,Vt,Rb,attb; overlays: o2b, g
  ushort* qb   = (ushort*)regB;
  ushort* kb   = (ushort*)(regB + 4194304);
  ushort* Vt   = (ushort*)(regB + 9437184);
  ushort* Rb   = (ushort*)(regB + 14680064);
  ushort* attb = (ushort*)(regB + 15990784);
  float*  o2b  = (float*)regB;            // Wo z=1 partial
  ushort* g    = (ushort*)regB;           // FFN1 out

  float*  o2 = (float*)take(8388608);     // Wo z=0 partial; later FFN2 z1 partial
  float*  h  = (float*)take(8388608);
  ushort* hb = (ushort*)take(4194304);

  float* p2 = (float*)WqT;                // FFN2 z2 partial
  float* p3 = (float*)W1T;                // FFN2 z3 partial

  prep_kernel<<<17152, 256, 0, stream>>>(x, mem, Wq, Wk, Wv, Wo, Wr, W1, W2,
                                         WqT, WkT, WvT, WoT, WrT, W1T, W2T, kvb, remb);

  proj8p<<<244, 512, 98304, stream>>>(kvb, WqT, WkT, WrT, remb, qb, kb, Vt, Rb);

  attn_mfma5<<<512, 256, 0, stream>>>(qb, kb, Vt, Rb, u, v, attb);

  // Wo: 8-phase SK2, 128 blocks (z0->o2, z1->o2b)
  gemm8p2_kern<1, 2><<<128, 512, 98304, stream>>>(attb, WoT, o2, o2b, nullptr, nullptr,
                                                  nullptr, 2048, 1024, 512, 1024, 4);
  ln_kernel<<<2048, 256, 0, stream>>>(x, o2, o2b, nullptr, nullptr, ln1g, ln1b, h, hb);

  // FFN1: 8-phase 128x256, 256 blocks (full chip)
  gemm8p2_kern<2, 1><<<256, 512, 98304, stream>>>(hb, W1T, g, nullptr, nullptr, nullptr,
                                                  b1, 2048, 4096, 1024, 1024, 16);

  // FFN2: 8-phase SK4, 256 blocks (z0->fbuf(+b2), z1->o2, z2->p2, z3->p3)
  gemm8p2_kern<3, 4><<<256, 512, 98304, stream>>>(g, W2T, fbuf, o2, p2, p3,
                                                  b2, 2048, 1024, 1024, 4096, 4);
  ln_kernel<<<2048, 256, 0, stream>>>(h, fbuf, o2, p2, p3, ln2g, ln2b, out, nullptr);
}